// Round 12
// baseline (141.843 us; speedup 1.0000x reference)
//
#include <hip/hip_runtime.h>

#define LOG2E 1.4426950408889634f
#define LN2 0.6931471805599453f

typedef __attribute__((ext_vector_type(8))) short bf16x8;
typedef __attribute__((ext_vector_type(4))) float f32x4;
typedef __attribute__((ext_vector_type(2))) float f32x2;

constexpr int Ee = 768;
constexpr int BN = 512;
// ws layout (floats):
constexpr long QC_OFF = 0;              // q       [512][768]
constexpr long KT_OFF = 393216;         // keysT   [768][512]
constexpr long VC_OFF = 786432;         // v       [512][768]
constexpr long KM_OFF = 1179648;        // kmT     [768][512]
constexpr long EN_OFF = 1572864;        // energy  [24][256][256]
constexpr long OA_OFF = 3145728;        // out_attn[512][768]

__device__ __forceinline__ unsigned pk_hi(float x0, float x1) {
    return (__float_as_uint(x0) >> 16) | (__float_as_uint(x1) & 0xFFFF0000u);
}
__device__ __forceinline__ float rhi(float x) {
    return __uint_as_float(__float_as_uint(x) & 0xFFFF0000u);
}
__device__ __forceinline__ f32x2 pk_fma2(f32x2 a, f32x2 b, f32x2 c) {
    f32x2 d;
    asm("v_pk_fma_f32 %0, %1, %2, %3" : "=v"(d) : "v"(a), "v"(b), "v"(c));
    return d;
}
__device__ __forceinline__ f32x2 pk_add2(f32x2 a, f32x2 b) {
    f32x2 d;
    asm("v_pk_add_f32 %0, %1, %2" : "=v"(d) : "v"(a), "v"(b));
    return d;
}

// packed fast exp2: Schraudolph magic-round + deg-4 Taylor on frac.
// Valid for t <= ~14 (our t <= ~13); clamps t >= -126. Rel err <= 6e-5.
__device__ __forceinline__ f32x2 fexp2(f32x2 t) {
    t.x = fmaxf(t.x, -126.0f);
    t.y = fmaxf(t.y, -126.0f);
    const float MG = 12582912.0f;                 // 1.5 * 2^23
    f32x2 r = pk_add2(t, (f32x2){MG, MG});        // round(t) in mantissa
    f32x2 g = pk_add2(r, (f32x2){-MG, -MG});      // round(t) as float
    f32x2 f = pk_fma2(g, (f32x2){-1.f, -1.f}, t); // frac in [-0.5, 0.5]
    f32x2 p = pk_fma2(f, (f32x2){0.0096181292f, 0.0096181292f},
                         (f32x2){0.0555041087f, 0.0555041087f});
    p = pk_fma2(f, p, (f32x2){0.2402265070f, 0.2402265070f});
    p = pk_fma2(f, p, (f32x2){0.6931471806f, 0.6931471806f});
    p = pk_fma2(f, p, (f32x2){1.0f, 1.0f});
    const unsigned b0 = __float_as_uint(p.x) + (__float_as_uint(r.x) << 23);
    const unsigned b1 = __float_as_uint(p.y) + (__float_as_uint(r.y) << 23);
    return (f32x2){__uint_as_float(b0), __uint_as_float(b1)};
}

// ------------- bf16 hi/lo split MFMA GEMM, 64x64 tile, BK=32 ---------------
// C = A@B as AhBh + AhBl + AlBh (bf16 MFMA, fp32 accum). 256 thr = 4 waves;
// wave = 32x32 quadrant = 2x2 frags of v_mfma_f32_16x16x32_bf16.
// tid<128 stage B (in-reg 4x4 transpose -> BsT[n][k]), tid>=128 stage A.
// XOR swizzle (row&7)<<4 on 128B rows. EPI=1: qkv scatter epilogue.
template<int EPI>
__global__ __launch_bounds__(256)
void mfma_gemm(const float* __restrict__ A, int lda, long sAb, long sAh,
               const float* __restrict__ Bm, int ldb, long sBb, long sBh,
               float* __restrict__ C, int ldc, long sCb, long sCh,
               const float* __restrict__ bias, int K, int Hdiv,
               float* __restrict__ eq, float* __restrict__ ek,
               float* __restrict__ ev)
{
    __shared__ __align__(16) unsigned short sm[4 * 64 * 64]; // Ahi,Alo,Bhi,Blo
    char* const smb = (char*)sm;
    const int tid = threadIdx.x;
    const int m0 = blockIdx.x * 64, n0 = blockIdx.y * 64;
    const int zb = blockIdx.z / Hdiv, zh = blockIdx.z - zb * Hdiv;
    A  += zb * sAb + zh * sAh;
    Bm += zb * sBb + zh * sBh;
    C  += zb * sCb + zh * sCh;

    const int lane = tid & 63, w = tid >> 6;
    const int wr = w >> 1, wc = w & 1;
    const int fr = lane & 15, fko2 = (lane >> 4) * 16;

    const bool isB = tid < 128;
    const int kq = isB ? (tid >> 4) : ((tid - 128) & 7);
    const int nq = tid & 15;
    const int mq = (tid - 128) >> 3;

    auto foff = [](int plane, int row, int cb) {
        return plane * 8192 + row * 128 + (cb ^ ((row & 7) << 4));
    };
    int wo[8];
    if (isB) {
        #pragma unroll
        for (int e = 0; e < 4; ++e) {
            wo[e]     = foff(2, nq * 4 + e, kq * 8);
            wo[e + 4] = foff(3, nq * 4 + e, kq * 8);
        }
    } else {
        #pragma unroll
        for (int r = 0; r < 4; ++r) {
            wo[r]     = foff(0, mq * 4 + r, kq * 8);
            wo[r + 4] = foff(1, mq * 4 + r, kq * 8);
        }
    }
    const int oA0h = foff(0, wr * 32 + fr,      fko2);
    const int oA1h = foff(0, wr * 32 + 16 + fr, fko2);
    const int oA0l = oA0h + 8192, oA1l = oA1h + 8192;
    const int oB0h = foff(2, wc * 32 + fr,      fko2);
    const int oB1h = foff(2, wc * 32 + 16 + fr, fko2);
    const int oB0l = oB0h + 8192, oB1l = oB1h + 8192;

    f32x4 acc00 = {}, acc01 = {}, acc10 = {}, acc11 = {};
    float4 r0, r1, r2, r3;

    auto load_regs = [&](int k0) {
        if (isB) {
            const float* p = &Bm[(long)(k0 + kq * 4) * ldb + n0 + nq * 4];
            r0 = *(const float4*)p; p += ldb;
            r1 = *(const float4*)p; p += ldb;
            r2 = *(const float4*)p; p += ldb;
            r3 = *(const float4*)p;
        } else {
            const float* p = &A[(long)(m0 + mq * 4) * lda + k0 + kq * 4];
            r0 = *(const float4*)p; p += lda;
            r1 = *(const float4*)p; p += lda;
            r2 = *(const float4*)p; p += lda;
            r3 = *(const float4*)p;
        }
    };

    auto cvt_store = [&](const float4& v, int o_hi, int o_lo) {
        uint2 hi; hi.x = pk_hi(v.x, v.y); hi.y = pk_hi(v.z, v.w);
        const float l0 = v.x - rhi(v.x), l1 = v.y - rhi(v.y);
        const float l2 = v.z - rhi(v.z), l3 = v.w - rhi(v.w);
        uint2 lo; lo.x = pk_hi(l0, l1); lo.y = pk_hi(l2, l3);
        *(uint2*)(smb + o_hi) = hi;
        *(uint2*)(smb + o_lo) = lo;
    };

    auto stage = [&]() {
        if (isB) {
            #pragma unroll
            for (int e = 0; e < 4; ++e) {
                float4 col;
                col.x = (&r0.x)[e]; col.y = (&r1.x)[e];
                col.z = (&r2.x)[e]; col.w = (&r3.x)[e];
                cvt_store(col, wo[e], wo[e + 4]);
            }
        } else {
            cvt_store(r0, wo[0], wo[4]);
            cvt_store(r1, wo[1], wo[5]);
            cvt_store(r2, wo[2], wo[6]);
            cvt_store(r3, wo[3], wo[7]);
        }
    };

    load_regs(0);
    for (int k0 = 0; k0 < K; k0 += 32) {
        __syncthreads();
        stage();
        __syncthreads();
        if (k0 + 32 < K) load_regs(k0 + 32);
        const bf16x8 Ah0 = *(const bf16x8*)(smb + oA0h);
        const bf16x8 Ah1 = *(const bf16x8*)(smb + oA1h);
        const bf16x8 Al0 = *(const bf16x8*)(smb + oA0l);
        const bf16x8 Al1 = *(const bf16x8*)(smb + oA1l);
        const bf16x8 Bh0 = *(const bf16x8*)(smb + oB0h);
        const bf16x8 Bh1 = *(const bf16x8*)(smb + oB1h);
        const bf16x8 Bl0 = *(const bf16x8*)(smb + oB0l);
        const bf16x8 Bl1 = *(const bf16x8*)(smb + oB1l);
        acc00 = __builtin_amdgcn_mfma_f32_16x16x32_bf16(Ah0, Bh0, acc00, 0, 0, 0);
        acc01 = __builtin_amdgcn_mfma_f32_16x16x32_bf16(Ah0, Bh1, acc01, 0, 0, 0);
        acc10 = __builtin_amdgcn_mfma_f32_16x16x32_bf16(Ah1, Bh0, acc10, 0, 0, 0);
        acc11 = __builtin_amdgcn_mfma_f32_16x16x32_bf16(Ah1, Bh1, acc11, 0, 0, 0);
        acc00 = __builtin_amdgcn_mfma_f32_16x16x32_bf16(Ah0, Bl0, acc00, 0, 0, 0);
        acc01 = __builtin_amdgcn_mfma_f32_16x16x32_bf16(Ah0, Bl1, acc01, 0, 0, 0);
        acc10 = __builtin_amdgcn_mfma_f32_16x16x32_bf16(Ah1, Bl0, acc10, 0, 0, 0);
        acc11 = __builtin_amdgcn_mfma_f32_16x16x32_bf16(Ah1, Bl1, acc11, 0, 0, 0);
        acc00 = __builtin_amdgcn_mfma_f32_16x16x32_bf16(Al0, Bh0, acc00, 0, 0, 0);
        acc01 = __builtin_amdgcn_mfma_f32_16x16x32_bf16(Al0, Bh1, acc01, 0, 0, 0);
        acc10 = __builtin_amdgcn_mfma_f32_16x16x32_bf16(Al1, Bh0, acc10, 0, 0, 0);
        acc11 = __builtin_amdgcn_mfma_f32_16x16x32_bf16(Al1, Bh1, acc11, 0, 0, 0);
    }

    const int rb = m0 + wr * 32 + (lane >> 4) * 4;
    const int cb = n0 + wc * 32 + fr;
    if (EPI == 1) {
        auto scat = [&](int row, int col, float x) {
            x += bias[col];
            const int i = col / 3, s = col - i * 3;
            if (s == 0)      eq[(long)row * Ee + i] = x;
            else if (s == 1) ek[(long)i * BN + row] = x;
            else             ev[(long)row * Ee + i] = x;
        };
        #pragma unroll
        for (int j = 0; j < 4; ++j) {
            scat(rb + j,      cb,      acc00[j]);
            scat(rb + j,      cb + 16, acc01[j]);
            scat(rb + j + 16, cb,      acc10[j]);
            scat(rb + j + 16, cb + 16, acc11[j]);
        }
    } else {
        const float b0  = bias ? bias[cb]      : 0.f;
        const float b16 = bias ? bias[cb + 16] : 0.f;
        #pragma unroll
        for (int j = 0; j < 4; ++j) C[(long)(rb + j +  0) * ldc + cb +  0] = acc00[j] + b0;
        #pragma unroll
        for (int j = 0; j < 4; ++j) C[(long)(rb + j +  0) * ldc + cb + 16] = acc01[j] + b16;
        #pragma unroll
        for (int j = 0; j < 4; ++j) C[(long)(rb + j + 16) * ldc + cb +  0] = acc10[j] + b0;
        #pragma unroll
        for (int j = 0; j < 4; ++j) C[(long)(rb + j + 16) * ldc + cb + 16] = acc11[j] + b16;
    }
}

// ---------------- Gaussian-mixture logsumexp (R=8, j-split x8, packed) -----
// block = one i, 512 thr (8 waves). wave = j-group (96 j), lane = 8 rows.
// All math packed fp32; exp2 via fexp2 (no trans-pipe ops in the hot loop).
__global__ __launch_bounds__(512)
void k_mixture(const float* __restrict__ mean, const float* __restrict__ logvar,
               const float* __restrict__ mix, const float* __restrict__ keysT,
               float* __restrict__ kmT)
{
    __shared__ __align__(16) float aS[768], bS[768], cS[768];
    __shared__ float sP[512][9];
    const int i = blockIdx.x;
    const int tid = threadIdx.x;

    for (int j = tid; j < 768; j += 512) {
        const float lv = logvar[i * Ee + j];
        const float mu = mean[i * Ee + j];
        const float istd2 = __builtin_amdgcn_exp2f(-lv * LOG2E);
        aS[j] = -0.5f * LOG2E * istd2;
        bS[j] = LOG2E * mu * istd2;
        cS[j] = fmaf(-0.5f * LOG2E * mu * mu, istd2, LOG2E * (mix[j] - 0.5f * lv));
    }
    __syncthreads();

    const int rg = tid & 63;
    const int jg = tid >> 6;
    f32x2 kvd[8], k2d[8], s2[8];
    #pragma unroll
    for (int q = 0; q < 8; ++q) {
        const float kv = keysT[(long)i * BN + q * 64 + rg];
        const float k2 = kv * kv;
        kvd[q] = (f32x2){kv, kv};
        k2d[q] = (f32x2){k2, k2};
        s2[q] = (f32x2){0.f, 0.f};
    }
    const float4* a4 = (const float4*)(aS + jg * 96);
    const float4* b4 = (const float4*)(bS + jg * 96);
    const float4* c4 = (const float4*)(cS + jg * 96);
    for (int it = 0; it < 24; ++it) {
        const float4 a = a4[it], b = b4[it], c = c4[it];
        const f32x2 a01 = {a.x, a.y}, a23 = {a.z, a.w};
        const f32x2 b01 = {b.x, b.y}, b23 = {b.z, b.w};
        const f32x2 c01 = {c.x, c.y}, c23 = {c.z, c.w};
        #pragma unroll
        for (int q = 0; q < 8; ++q) {
            f32x2 t0 = pk_fma2(a01, k2d[q], pk_fma2(b01, kvd[q], c01));
            f32x2 t1 = pk_fma2(a23, k2d[q], pk_fma2(b23, kvd[q], c23));
            s2[q] = pk_add2(s2[q], fexp2(t0));
            s2[q] = pk_add2(s2[q], fexp2(t1));
        }
    }
    #pragma unroll
    for (int q = 0; q < 8; ++q)
        sP[q * 64 + rg][jg] = s2[q].x + s2[q].y;
    __syncthreads();

    const float* rp = sP[tid];
    const float t0 = ((rp[0] + rp[1]) + (rp[2] + rp[3]))
                   + ((rp[4] + rp[5]) + (rp[6] + rp[7]));
    kmT[(long)i * BN + tid] = LN2 * __builtin_amdgcn_logf(t0);
}

// ------------- fused softmax + PV: oat tile = softmax(E band) @ v ----------
// block = (row-tile of 64, bh). Phase 1: load 64x256 energy band, wave row
// max/sum (shfl_xor 1,2), scale by 1/(sum*sqrt768), pack bf16 hi/lo att into
// LDS A-planes (512B rows, XOR swizzle). Phase 2: 8-step MFMA loop, only B
// (v) restaged per K-step.
__global__ __launch_bounds__(256)
void k_smpv(const float* __restrict__ energy, const float* __restrict__ vc,
            float* __restrict__ oat)
{
    __shared__ __align__(16) unsigned short att[32768]; // hi(32KB) + lo(32KB)
    __shared__ __align__(16) unsigned short bv[8192];   // v hi(8KB) + lo(8KB)
    char* const attb = (char*)att;
    char* const bvb  = (char*)bv;
    const int tid = threadIdx.x;
    const int tile = blockIdx.x, bh = blockIdx.y;
    const int b = bh / 12, h = bh - b * 12;
    const float* E = energy + (long)bh * 65536 + (long)tile * 64 * 256;
    const float* V = vc + (long)b * 196608 + h * 64;
    float* O = oat + ((long)b * 256 + tile * 64) * 768 + h * 64;

    const int w = tid >> 6, lane = tid & 63;

    // ---- phase 1: softmax of 64x256 band into att planes ----
    {
        const int rl = w * 16 + (lane >> 2);   // local row 0..63
        const int mq = (lane & 3) * 64;        // m-quarter base
        float4 ev[16];
        const float* erow = E + (long)rl * 256 + mq;
        #pragma unroll
        for (int t = 0; t < 16; ++t) ev[t] = *(const float4*)(erow + t * 4);
        float mx = -__builtin_inff();
        #pragma unroll
        for (int t = 0; t < 16; ++t)
            mx = fmaxf(mx, fmaxf(fmaxf(ev[t].x, ev[t].y), fmaxf(ev[t].z, ev[t].w)));
        mx = fmaxf(mx, __shfl_xor(mx, 1, 64));
        mx = fmaxf(mx, __shfl_xor(mx, 2, 64));
        float sum = 0.f;
        #pragma unroll
        for (int t = 0; t < 16; ++t) {
            ev[t].x = __builtin_amdgcn_exp2f((ev[t].x - mx) * LOG2E);
            ev[t].y = __builtin_amdgcn_exp2f((ev[t].y - mx) * LOG2E);
            ev[t].z = __builtin_amdgcn_exp2f((ev[t].z - mx) * LOG2E);
            ev[t].w = __builtin_amdgcn_exp2f((ev[t].w - mx) * LOG2E);
            sum += (ev[t].x + ev[t].y) + (ev[t].z + ev[t].w);
        }
        sum += __shfl_xor(sum, 1, 64);
        sum += __shfl_xor(sum, 2, 64);
        const float sc = 1.0f / (sum * 27.712812921102035f);  // * sqrt(768)
        const int rxor = (rl & 7) << 4;
        #pragma unroll
        for (int t = 0; t < 16; ++t) {
            const float x0 = ev[t].x * sc, x1 = ev[t].y * sc;
            const float x2 = ev[t].z * sc, x3 = ev[t].w * sc;
            uint2 hi; hi.x = pk_hi(x0, x1); hi.y = pk_hi(x2, x3);
            const float l0 = x0 - rhi(x0), l1 = x1 - rhi(x1);
            const float l2 = x2 - rhi(x2), l3 = x3 - rhi(x3);
            uint2 lo; lo.x = pk_hi(l0, l1); lo.y = pk_hi(l2, l3);
            const int cb = (mq + t * 4) * 2;
            *(uint2*)(attb + (long)rl * 512 + (cb ^ rxor))         = hi;
            *(uint2*)(attb + 32768 + (long)rl * 512 + (cb ^ rxor)) = lo;
        }
    }

    // ---- phase 2: [64 rows] x [64 d] = att(64x256) @ v(256x64) ----
    const int wr = w >> 1, wc = w & 1;
    const int fr = lane & 15, fko2 = (lane >> 4) * 16;
    const int rA0 = wr * 32 + fr, rA1 = rA0 + 16;
    const int rB0 = wc * 32 + fr, rB1 = rB0 + 16;
    const int xA0 = (rA0 & 7) << 4, xA1 = (rA1 & 7) << 4;
    const int oB0h = rB0 * 128 + (fko2 ^ ((rB0 & 7) << 4));
    const int oB1h = rB1 * 128 + (fko2 ^ ((rB1 & 7) << 4));
    const int oB0l = oB0h + 8192, oB1l = oB1h + 8192;

    const bool isB = tid < 128;
    const int kq = tid >> 4;
    const int nq = tid & 15;
    int wo[8];
    #pragma unroll
    for (int e = 0; e < 4; ++e) {
        const int row = nq * 4 + e;
        wo[e]     = row * 128 + ((kq * 8) ^ ((row & 7) << 4));
        wo[e + 4] = wo[e] + 8192;
    }

    f32x4 acc00 = {}, acc01 = {}, acc10 = {}, acc11 = {};
    float4 r0, r1, r2, r3;
    auto load_regs = [&](int k0) {
        if (isB) {
            const float* p = &V[(long)(k0 + kq * 4) * 768 + nq * 4];
            r0 = *(const float4*)p; p += 768;
            r1 = *(const float4*)p; p += 768;
            r2 = *(const float4*)p; p += 768;
            r3 = *(const float4*)p;
        }
    };
    auto cvt_store = [&](const float4& v, int o_hi, int o_lo) {
        uint2 hi; hi.x = pk_hi(v.x, v.y); hi.y = pk_hi(v.z, v.w);
        const float l0 = v.x - rhi(v.x), l1 = v.y - rhi(v.y);
        const float l2 = v.z - rhi(v.z), l3 = v.w - rhi(v.w);
        uint2 lo; lo.x = pk_hi(l0, l1); lo.y = pk_hi(l2, l3);
        *(uint2*)(bvb + o_hi) = hi;
        *(uint2*)(bvb + o_lo) = lo;
    };

    load_regs(0);
    for (int k0 = 0; k0 < 256; k0 += 32) {
        __syncthreads();
        if (isB) {
            #pragma unroll
            for (int e = 0; e < 4; ++e) {
                float4 col;
                col.x = (&r0.x)[e]; col.y = (&r1.x)[e];
                col.z = (&r2.x)[e]; col.w = (&r3.x)[e];
                cvt_store(col, wo[e], wo[e + 4]);
            }
        }
        __syncthreads();
        if (k0 + 32 < 256) load_regs(k0 + 32);
        const int cA = k0 * 2 + fko2;
        const bf16x8 Ah0 = *(const bf16x8*)(attb + (long)rA0 * 512 + (cA ^ xA0));
        const bf16x8 Ah1 = *(const bf16x8*)(attb + (long)rA1 * 512 + (cA ^ xA1));
        const bf16x8 Al0 = *(const bf16x8*)(attb + 32768 + (long)rA0 * 512 + (cA ^ xA0));
        const bf16x8 Al1 = *(const bf16x8*)(attb + 32768 + (long)rA1 * 512 + (cA ^ xA1));
        const bf16x8 Bh0 = *(const bf16x8*)(bvb + oB0h);
        const bf16x8 Bh1 = *(const bf16x8*)(bvb + oB1h);
        const bf16x8 Bl0 = *(const bf16x8*)(bvb + oB0l);
        const bf16x8 Bl1 = *(const bf16x8*)(bvb + oB1l);
        acc00 = __builtin_amdgcn_mfma_f32_16x16x32_bf16(Ah0, Bh0, acc00, 0, 0, 0);
        acc01 = __builtin_amdgcn_mfma_f32_16x16x32_bf16(Ah0, Bh1, acc01, 0, 0, 0);
        acc10 = __builtin_amdgcn_mfma_f32_16x16x32_bf16(Ah1, Bh0, acc10, 0, 0, 0);
        acc11 = __builtin_amdgcn_mfma_f32_16x16x32_bf16(Ah1, Bh1, acc11, 0, 0, 0);
        acc00 = __builtin_amdgcn_mfma_f32_16x16x32_bf16(Ah0, Bl0, acc00, 0, 0, 0);
        acc01 = __builtin_amdgcn_mfma_f32_16x16x32_bf16(Ah0, Bl1, acc01, 0, 0, 0);
        acc10 = __builtin_amdgcn_mfma_f32_16x16x32_bf16(Ah1, Bl0, acc10, 0, 0, 0);
        acc11 = __builtin_amdgcn_mfma_f32_16x16x32_bf16(Ah1, Bl1, acc11, 0, 0, 0);
        acc00 = __builtin_amdgcn_mfma_f32_16x16x32_bf16(Al0, Bh0, acc00, 0, 0, 0);
        acc01 = __builtin_amdgcn_mfma_f32_16x16x32_bf16(Al0, Bh1, acc01, 0, 0, 0);
        acc10 = __builtin_amdgcn_mfma_f32_16x16x32_bf16(Al1, Bh0, acc10, 0, 0, 0);
        acc11 = __builtin_amdgcn_mfma_f32_16x16x32_bf16(Al1, Bh1, acc11, 0, 0, 0);
    }

    const int rb = wr * 32 + (lane >> 4) * 4;
    const int cb = wc * 32 + fr;
    #pragma unroll
    for (int j = 0; j < 4; ++j) O[(long)(rb + j +  0) * 768 + cb +  0] = acc00[j];
    #pragma unroll
    for (int j = 0; j < 4; ++j) O[(long)(rb + j +  0) * 768 + cb + 16] = acc01[j];
    #pragma unroll
    for (int j = 0; j < 4; ++j) O[(long)(rb + j + 16) * 768 + cb +  0] = acc10[j];
    #pragma unroll
    for (int j = 0; j < 4; ++j) O[(long)(rb + j + 16) * 768 + cb + 16] = acc11[j];
}

extern "C" void kernel_launch(void* const* d_in, const int* in_sizes, int n_in,
                              void* d_out, int out_size, void* d_ws, size_t ws_size,
                              hipStream_t stream)
{
    (void)in_sizes; (void)n_in; (void)out_size; (void)ws_size;
    const float* x      = (const float*)d_in[0];
    const float* Wqkv   = (const float*)d_in[1];
    const float* bqkv   = (const float*)d_in[2];
    const float* Wproj  = (const float*)d_in[3];
    const float* bproj  = (const float*)d_in[4];
    const float* mean   = (const float*)d_in[5];
    const float* logvar = (const float*)d_in[6];
    const float* mixc   = (const float*)d_in[7];
    float* out = (float*)d_out;
    float* ws = (float*)d_ws;
    float* qc     = ws + QC_OFF;
    float* keysT  = ws + KT_OFF;
    float* vc     = ws + VC_OFF;
    float* kmT    = ws + KM_OFF;
    float* energy = ws + EN_OFF;
    float* oat    = ws + OA_OFF;

    // 1) qkv = x @ Wqkv + bqkv, scatter epilogue -> q / keysT / v
    mfma_gemm<1><<<dim3(8,36,1),256,0,stream>>>(
        x,768,0,0, Wqkv,2304,0,0, nullptr,0,0,0, bqkv, 768, 1,
        qc, keysT, vc);
    // 2) key_mix (transposed output kmT[i][row])
    k_mixture<<<768,512,0,stream>>>(mean, logvar, mixc, keysT, kmT);
    // 3) energy[b,h,q,k] = sum_d q[.,d] * kmT[d][k]
    mfma_gemm<0><<<dim3(4,4,24),256,0,stream>>>(
        qc,768,196608,64, kmT,512,256,32768, energy,256,786432,65536,
        nullptr, 64, 12, nullptr,nullptr,nullptr);
    // 4+5) fused: att = softmax(energy)/sqrt(768); out_attn = att @ v
    k_smpv<<<dim3(4,24,1),256,0,stream>>>(energy, vc, oat);
    // 6) out = out_attn @ Wproj + bproj
    mfma_gemm<0><<<dim3(8,12,1),256,0,stream>>>(
        oat,768,0,0, Wproj,768,0,0, out,768,0,0, bproj, 768, 1,
        nullptr,nullptr,nullptr);
}

// Round 13
// 113.527 us; speedup vs baseline: 1.2494x; 1.2494x over previous
//
#include <hip/hip_runtime.h>

#define LOG2E 1.4426950408889634f
#define LN2 0.6931471805599453f

typedef __attribute__((ext_vector_type(8))) short bf16x8;
typedef __attribute__((ext_vector_type(4))) float f32x4;
typedef __attribute__((ext_vector_type(2))) float f32x2;

constexpr int Ee = 768;
constexpr int BN = 512;
// ws layout (floats):
constexpr long QC_OFF = 0;              // q       [512][768]
constexpr long KT_OFF = 393216;         // keysT   [768][512]
constexpr long VC_OFF = 786432;         // v       [512][768]
constexpr long KM_OFF = 1179648;        // kmT     [768][512]
constexpr long EN_OFF = 1572864;        // energy  [24][256][256]
constexpr long OA_OFF = 3145728;        // out_attn[512][768]

__device__ __forceinline__ unsigned pk_hi(float x0, float x1) {
    return (__float_as_uint(x0) >> 16) | (__float_as_uint(x1) & 0xFFFF0000u);
}
__device__ __forceinline__ float rhi(float x) {
    return __uint_as_float(__float_as_uint(x) & 0xFFFF0000u);
}
__device__ __forceinline__ f32x2 pk_fma2(f32x2 a, f32x2 b, f32x2 c) {
    f32x2 d;
    asm("v_pk_fma_f32 %0, %1, %2, %3" : "=v"(d) : "v"(a), "v"(b), "v"(c));
    return d;
}
__device__ __forceinline__ f32x2 pk_add2(f32x2 a, f32x2 b) {
    f32x2 d;
    asm("v_pk_add_f32 %0, %1, %2" : "=v"(d) : "v"(a), "v"(b));
    return d;
}

// ------------- bf16 hi/lo split MFMA GEMM, 64x64 tile, BK=32 ---------------
// C = A@B as AhBh + AhBl + AlBh (bf16 MFMA, fp32 accum). 256 thr = 4 waves;
// wave = 32x32 quadrant = 2x2 frags of v_mfma_f32_16x16x32_bf16.
// tid<128 stage B (in-reg 4x4 transpose -> BsT[n][k]), tid>=128 stage A.
// XOR swizzle (row&7)<<4 on 128B rows. DOUBLE-BUFFERED LDS (2x32KB): one
// barrier per K-step; stage of tile k+1 overlaps MFMA of tile k.
// EPI=1: qkv scatter epilogue.
template<int EPI>
__global__ __launch_bounds__(256)
void mfma_gemm(const float* __restrict__ A, int lda, long sAb, long sAh,
               const float* __restrict__ Bm, int ldb, long sBb, long sBh,
               float* __restrict__ C, int ldc, long sCb, long sCh,
               const float* __restrict__ bias, int K, int Hdiv,
               float* __restrict__ eq, float* __restrict__ ek,
               float* __restrict__ ev)
{
    __shared__ __align__(16) unsigned short sm[2 * 4 * 64 * 64]; // 2 bufs x 4 planes
    char* const smb = (char*)sm;
    const int tid = threadIdx.x;
    const int m0 = blockIdx.x * 64, n0 = blockIdx.y * 64;
    const int zb = blockIdx.z / Hdiv, zh = blockIdx.z - zb * Hdiv;
    A  += zb * sAb + zh * sAh;
    Bm += zb * sBb + zh * sBh;
    C  += zb * sCb + zh * sCh;

    const int lane = tid & 63, w = tid >> 6;
    const int wr = w >> 1, wc = w & 1;
    const int fr = lane & 15, fko2 = (lane >> 4) * 16;

    const bool isB = tid < 128;
    const int kq = isB ? (tid >> 4) : ((tid - 128) & 7);
    const int nq = tid & 15;
    const int mq = (tid - 128) >> 3;

    auto foff = [](int plane, int row, int cb) {
        return plane * 8192 + row * 128 + (cb ^ ((row & 7) << 4));
    };
    int wo[8];
    if (isB) {
        #pragma unroll
        for (int e = 0; e < 4; ++e) {
            wo[e]     = foff(2, nq * 4 + e, kq * 8);
            wo[e + 4] = foff(3, nq * 4 + e, kq * 8);
        }
    } else {
        #pragma unroll
        for (int r = 0; r < 4; ++r) {
            wo[r]     = foff(0, mq * 4 + r, kq * 8);
            wo[r + 4] = foff(1, mq * 4 + r, kq * 8);
        }
    }
    const int oA0h = foff(0, wr * 32 + fr,      fko2);
    const int oA1h = foff(0, wr * 32 + 16 + fr, fko2);
    const int oA0l = oA0h + 8192, oA1l = oA1h + 8192;
    const int oB0h = foff(2, wc * 32 + fr,      fko2);
    const int oB1h = foff(2, wc * 32 + 16 + fr, fko2);
    const int oB0l = oB0h + 8192, oB1l = oB1h + 8192;

    f32x4 acc00 = {}, acc01 = {}, acc10 = {}, acc11 = {};
    float4 r0, r1, r2, r3;

    auto load_regs = [&](int k0) {
        if (isB) {
            const float* p = &Bm[(long)(k0 + kq * 4) * ldb + n0 + nq * 4];
            r0 = *(const float4*)p; p += ldb;
            r1 = *(const float4*)p; p += ldb;
            r2 = *(const float4*)p; p += ldb;
            r3 = *(const float4*)p;
        } else {
            const float* p = &A[(long)(m0 + mq * 4) * lda + k0 + kq * 4];
            r0 = *(const float4*)p; p += lda;
            r1 = *(const float4*)p; p += lda;
            r2 = *(const float4*)p; p += lda;
            r3 = *(const float4*)p;
        }
    };

    auto cvt_store = [&](const float4& v, int o_hi, int o_lo) {
        uint2 hi; hi.x = pk_hi(v.x, v.y); hi.y = pk_hi(v.z, v.w);
        const float l0 = v.x - rhi(v.x), l1 = v.y - rhi(v.y);
        const float l2 = v.z - rhi(v.z), l3 = v.w - rhi(v.w);
        uint2 lo; lo.x = pk_hi(l0, l1); lo.y = pk_hi(l2, l3);
        *(uint2*)(smb + o_hi) = hi;
        *(uint2*)(smb + o_lo) = lo;
    };

    auto stage = [&](int bo) {
        if (isB) {
            #pragma unroll
            for (int e = 0; e < 4; ++e) {
                float4 col;
                col.x = (&r0.x)[e]; col.y = (&r1.x)[e];
                col.z = (&r2.x)[e]; col.w = (&r3.x)[e];
                cvt_store(col, bo + wo[e], bo + wo[e + 4]);
            }
        } else {
            cvt_store(r0, bo + wo[0], bo + wo[4]);
            cvt_store(r1, bo + wo[1], bo + wo[5]);
            cvt_store(r2, bo + wo[2], bo + wo[6]);
            cvt_store(r3, bo + wo[3], bo + wo[7]);
        }
    };

    load_regs(0);
    stage(0);
    __syncthreads();
    int bo = 0;
    for (int k0 = 0; k0 < K; k0 += 32) {
        const bool more = (k0 + 32 < K);
        if (more) load_regs(k0 + 32);
        const bf16x8 Ah0 = *(const bf16x8*)(smb + bo + oA0h);
        const bf16x8 Ah1 = *(const bf16x8*)(smb + bo + oA1h);
        const bf16x8 Al0 = *(const bf16x8*)(smb + bo + oA0l);
        const bf16x8 Al1 = *(const bf16x8*)(smb + bo + oA1l);
        const bf16x8 Bh0 = *(const bf16x8*)(smb + bo + oB0h);
        const bf16x8 Bh1 = *(const bf16x8*)(smb + bo + oB1h);
        const bf16x8 Bl0 = *(const bf16x8*)(smb + bo + oB0l);
        const bf16x8 Bl1 = *(const bf16x8*)(smb + bo + oB1l);
        acc00 = __builtin_amdgcn_mfma_f32_16x16x32_bf16(Ah0, Bh0, acc00, 0, 0, 0);
        acc01 = __builtin_amdgcn_mfma_f32_16x16x32_bf16(Ah0, Bh1, acc01, 0, 0, 0);
        acc10 = __builtin_amdgcn_mfma_f32_16x16x32_bf16(Ah1, Bh0, acc10, 0, 0, 0);
        acc11 = __builtin_amdgcn_mfma_f32_16x16x32_bf16(Ah1, Bh1, acc11, 0, 0, 0);
        acc00 = __builtin_amdgcn_mfma_f32_16x16x32_bf16(Ah0, Bl0, acc00, 0, 0, 0);
        acc01 = __builtin_amdgcn_mfma_f32_16x16x32_bf16(Ah0, Bl1, acc01, 0, 0, 0);
        acc10 = __builtin_amdgcn_mfma_f32_16x16x32_bf16(Ah1, Bl0, acc10, 0, 0, 0);
        acc11 = __builtin_amdgcn_mfma_f32_16x16x32_bf16(Ah1, Bl1, acc11, 0, 0, 0);
        acc00 = __builtin_amdgcn_mfma_f32_16x16x32_bf16(Al0, Bh0, acc00, 0, 0, 0);
        acc01 = __builtin_amdgcn_mfma_f32_16x16x32_bf16(Al0, Bh1, acc01, 0, 0, 0);
        acc10 = __builtin_amdgcn_mfma_f32_16x16x32_bf16(Al1, Bh0, acc10, 0, 0, 0);
        acc11 = __builtin_amdgcn_mfma_f32_16x16x32_bf16(Al1, Bh1, acc11, 0, 0, 0);
        if (more) stage(bo ^ 32768);
        __syncthreads();
        bo ^= 32768;
    }

    const int rb = m0 + wr * 32 + (lane >> 4) * 4;
    const int cb = n0 + wc * 32 + fr;
    if (EPI == 1) {
        auto scat = [&](int row, int col, float x) {
            x += bias[col];
            const int i = col / 3, s = col - i * 3;
            if (s == 0)      eq[(long)row * Ee + i] = x;
            else if (s == 1) ek[(long)i * BN + row] = x;
            else             ev[(long)row * Ee + i] = x;
        };
        #pragma unroll
        for (int j = 0; j < 4; ++j) {
            scat(rb + j,      cb,      acc00[j]);
            scat(rb + j,      cb + 16, acc01[j]);
            scat(rb + j + 16, cb,      acc10[j]);
            scat(rb + j + 16, cb + 16, acc11[j]);
        }
    } else {
        const float b0  = bias ? bias[cb]      : 0.f;
        const float b16 = bias ? bias[cb + 16] : 0.f;
        #pragma unroll
        for (int j = 0; j < 4; ++j) C[(long)(rb + j +  0) * ldc + cb +  0] = acc00[j] + b0;
        #pragma unroll
        for (int j = 0; j < 4; ++j) C[(long)(rb + j +  0) * ldc + cb + 16] = acc01[j] + b16;
        #pragma unroll
        for (int j = 0; j < 4; ++j) C[(long)(rb + j + 16) * ldc + cb +  0] = acc10[j] + b0;
        #pragma unroll
        for (int j = 0; j < 4; ++j) C[(long)(rb + j + 16) * ldc + cb + 16] = acc11[j] + b16;
    }
}

// ---------------- Gaussian-mixture logsumexp (R=8, j-split x8, packed) -----
// R10 version (39.5us, issue-floor): packed fp32 quadratic + HW v_exp_f32.
// (R12 lesson: software packed exp2 is 2.2x SLOWER -- 13 issue slots/2 evals
// vs the trans pipe's 16cyc but single-op cost. Keep hardware exp2.)
__global__ __launch_bounds__(512)
void k_mixture(const float* __restrict__ mean, const float* __restrict__ logvar,
               const float* __restrict__ mix, const float* __restrict__ keysT,
               float* __restrict__ kmT)
{
    __shared__ __align__(16) float aS[768], bS[768], cS[768];
    __shared__ float sP[512][9];
    const int i = blockIdx.x;
    const int tid = threadIdx.x;

    for (int j = tid; j < 768; j += 512) {
        const float lv = logvar[i * Ee + j];
        const float mu = mean[i * Ee + j];
        const float istd2 = __builtin_amdgcn_exp2f(-lv * LOG2E);
        aS[j] = -0.5f * LOG2E * istd2;
        bS[j] = LOG2E * mu * istd2;
        cS[j] = fmaf(-0.5f * LOG2E * mu * mu, istd2, LOG2E * (mix[j] - 0.5f * lv));
    }
    __syncthreads();

    const int rg = tid & 63;
    const int jg = tid >> 6;
    f32x2 kvd[8], k2d[8], s2[8];
    #pragma unroll
    for (int q = 0; q < 8; ++q) {
        const float kv = keysT[(long)i * BN + q * 64 + rg];
        const float k2 = kv * kv;
        kvd[q] = (f32x2){kv, kv};
        k2d[q] = (f32x2){k2, k2};
        s2[q] = (f32x2){0.f, 0.f};
    }
    const float4* a4 = (const float4*)(aS + jg * 96);
    const float4* b4 = (const float4*)(bS + jg * 96);
    const float4* c4 = (const float4*)(cS + jg * 96);
    for (int it = 0; it < 24; ++it) {
        const float4 a = a4[it], b = b4[it], c = c4[it];
        const f32x2 a01 = {a.x, a.y}, a23 = {a.z, a.w};
        const f32x2 b01 = {b.x, b.y}, b23 = {b.z, b.w};
        const f32x2 c01 = {c.x, c.y}, c23 = {c.z, c.w};
        #pragma unroll
        for (int q = 0; q < 8; ++q) {
            f32x2 t0 = pk_fma2(a01, k2d[q], pk_fma2(b01, kvd[q], c01));
            f32x2 t1 = pk_fma2(a23, k2d[q], pk_fma2(b23, kvd[q], c23));
            f32x2 e0 = { __builtin_amdgcn_exp2f(t0.x), __builtin_amdgcn_exp2f(t0.y) };
            f32x2 e1 = { __builtin_amdgcn_exp2f(t1.x), __builtin_amdgcn_exp2f(t1.y) };
            s2[q] = pk_add2(s2[q], e0);
            s2[q] = pk_add2(s2[q], e1);
        }
    }
    #pragma unroll
    for (int q = 0; q < 8; ++q)
        sP[q * 64 + rg][jg] = s2[q].x + s2[q].y;
    __syncthreads();

    const float* rp = sP[tid];
    const float t0 = ((rp[0] + rp[1]) + (rp[2] + rp[3]))
                   + ((rp[4] + rp[5]) + (rp[6] + rp[7]));
    kmT[(long)i * BN + tid] = LN2 * __builtin_amdgcn_logf(t0);
}

// ------------- fused softmax + PV: oat tile = softmax(E band) @ v ----------
// Phase 1: softmax of 64x256 energy band -> bf16 hi/lo att in LDS.
// Phase 2: PV MFMA loop; V restaged per K-step into DOUBLE-BUFFERED planes
// (one barrier per step).
__global__ __launch_bounds__(256)
void k_smpv(const float* __restrict__ energy, const float* __restrict__ vc,
            float* __restrict__ oat)
{
    __shared__ __align__(16) unsigned short att[32768]; // att hi(32KB)+lo(32KB)
    __shared__ __align__(16) unsigned short bvs[16384]; // 2 bufs x v hi/lo (16KB)
    char* const attb = (char*)att;
    char* const bvb  = (char*)bvs;
    const int tid = threadIdx.x;
    const int tile = blockIdx.x, bh = blockIdx.y;
    const int b = bh / 12, h = bh - b * 12;
    const float* E = energy + (long)bh * 65536 + (long)tile * 64 * 256;
    const float* V = vc + (long)b * 196608 + h * 64;
    float* O = oat + ((long)b * 256 + tile * 64) * 768 + h * 64;

    const int w = tid >> 6, lane = tid & 63;
    const bool isB = tid < 128;
    const int kq = tid >> 4;
    const int nq = tid & 15;

    float4 r0, r1, r2, r3;
    auto loadV = [&](int k0) {
        if (isB) {
            const float* p = &V[(long)(k0 + kq * 4) * 768 + nq * 4];
            r0 = *(const float4*)p; p += 768;
            r1 = *(const float4*)p; p += 768;
            r2 = *(const float4*)p; p += 768;
            r3 = *(const float4*)p;
        }
    };
    loadV(0);   // overlaps phase 1

    // ---- phase 1: softmax of 64x256 band into att planes ----
    {
        const int rl = w * 16 + (lane >> 2);   // local row 0..63
        const int mq = (lane & 3) * 64;        // m-quarter base
        float4 ev[16];
        const float* erow = E + (long)rl * 256 + mq;
        #pragma unroll
        for (int t = 0; t < 16; ++t) ev[t] = *(const float4*)(erow + t * 4);
        float mx = -__builtin_inff();
        #pragma unroll
        for (int t = 0; t < 16; ++t)
            mx = fmaxf(mx, fmaxf(fmaxf(ev[t].x, ev[t].y), fmaxf(ev[t].z, ev[t].w)));
        mx = fmaxf(mx, __shfl_xor(mx, 1, 64));
        mx = fmaxf(mx, __shfl_xor(mx, 2, 64));
        float sum = 0.f;
        #pragma unroll
        for (int t = 0; t < 16; ++t) {
            ev[t].x = __builtin_amdgcn_exp2f((ev[t].x - mx) * LOG2E);
            ev[t].y = __builtin_amdgcn_exp2f((ev[t].y - mx) * LOG2E);
            ev[t].z = __builtin_amdgcn_exp2f((ev[t].z - mx) * LOG2E);
            ev[t].w = __builtin_amdgcn_exp2f((ev[t].w - mx) * LOG2E);
            sum += (ev[t].x + ev[t].y) + (ev[t].z + ev[t].w);
        }
        sum += __shfl_xor(sum, 1, 64);
        sum += __shfl_xor(sum, 2, 64);
        const float sc = 1.0f / (sum * 27.712812921102035f);  // * sqrt(768)
        const int rxor = (rl & 7) << 4;
        #pragma unroll
        for (int t = 0; t < 16; ++t) {
            const float x0 = ev[t].x * sc, x1 = ev[t].y * sc;
            const float x2 = ev[t].z * sc, x3 = ev[t].w * sc;
            uint2 hi; hi.x = pk_hi(x0, x1); hi.y = pk_hi(x2, x3);
            const float l0 = x0 - rhi(x0), l1 = x1 - rhi(x1);
            const float l2 = x2 - rhi(x2), l3 = x3 - rhi(x3);
            uint2 lo; lo.x = pk_hi(l0, l1); lo.y = pk_hi(l2, l3);
            const int cb = (mq + t * 4) * 2;
            *(uint2*)(attb + (long)rl * 512 + (cb ^ rxor))         = hi;
            *(uint2*)(attb + 32768 + (long)rl * 512 + (cb ^ rxor)) = lo;
        }
    }

    // ---- phase 2: [64 rows] x [64 d] = att(64x256) @ v(256x64) ----
    const int wr = w >> 1, wc = w & 1;
    const int fr = lane & 15, fko2 = (lane >> 4) * 16;
    const int rA0 = wr * 32 + fr, rA1 = rA0 + 16;
    const int rB0 = wc * 32 + fr, rB1 = rB0 + 16;
    const int xA0 = (rA0 & 7) << 4, xA1 = (rA1 & 7) << 4;
    const int oB0h = rB0 * 128 + (fko2 ^ ((rB0 & 7) << 4));
    const int oB1h = rB1 * 128 + (fko2 ^ ((rB1 & 7) << 4));
    const int oB0l = oB0h + 8192, oB1l = oB1h + 8192;

    int wo[8];
    #pragma unroll
    for (int e = 0; e < 4; ++e) {
        const int row = nq * 4 + e;
        wo[e]     = row * 128 + ((kq * 8) ^ ((row & 7) << 4));
        wo[e + 4] = wo[e] + 8192;
    }
    auto stageV = [&](int bo) {
        if (isB) {
            #pragma unroll
            for (int e = 0; e < 4; ++e) {
                float4 col;
                col.x = (&r0.x)[e]; col.y = (&r1.x)[e];
                col.z = (&r2.x)[e]; col.w = (&r3.x)[e];
                const float4 v = col;
                uint2 hi; hi.x = pk_hi(v.x, v.y); hi.y = pk_hi(v.z, v.w);
                const float l0 = v.x - rhi(v.x), l1 = v.y - rhi(v.y);
                const float l2 = v.z - rhi(v.z), l3 = v.w - rhi(v.w);
                uint2 lo; lo.x = pk_hi(l0, l1); lo.y = pk_hi(l2, l3);
                *(uint2*)(bvb + bo + wo[e])     = hi;
                *(uint2*)(bvb + bo + wo[e + 4]) = lo;
            }
        }
    };

    f32x4 acc00 = {}, acc01 = {}, acc10 = {}, acc11 = {};
    stageV(0);
    __syncthreads();
    int bo = 0;
    for (int k0 = 0; k0 < 256; k0 += 32) {
        const bool more = (k0 + 32 < 256);
        if (more) loadV(k0 + 32);
        const int cA = k0 * 2 + fko2;
        const bf16x8 Ah0 = *(const bf16x8*)(attb + (long)rA0 * 512 + (cA ^ xA0));
        const bf16x8 Ah1 = *(const bf16x8*)(attb + (long)rA1 * 512 + (cA ^ xA1));
        const bf16x8 Al0 = *(const bf16x8*)(attb + 32768 + (long)rA0 * 512 + (cA ^ xA0));
        const bf16x8 Al1 = *(const bf16x8*)(attb + 32768 + (long)rA1 * 512 + (cA ^ xA1));
        const bf16x8 Bh0 = *(const bf16x8*)(bvb + bo + oB0h);
        const bf16x8 Bh1 = *(const bf16x8*)(bvb + bo + oB1h);
        const bf16x8 Bl0 = *(const bf16x8*)(bvb + bo + oB0l);
        const bf16x8 Bl1 = *(const bf16x8*)(bvb + bo + oB1l);
        acc00 = __builtin_amdgcn_mfma_f32_16x16x32_bf16(Ah0, Bh0, acc00, 0, 0, 0);
        acc01 = __builtin_amdgcn_mfma_f32_16x16x32_bf16(Ah0, Bh1, acc01, 0, 0, 0);
        acc10 = __builtin_amdgcn_mfma_f32_16x16x32_bf16(Ah1, Bh0, acc10, 0, 0, 0);
        acc11 = __builtin_amdgcn_mfma_f32_16x16x32_bf16(Ah1, Bh1, acc11, 0, 0, 0);
        acc00 = __builtin_amdgcn_mfma_f32_16x16x32_bf16(Ah0, Bl0, acc00, 0, 0, 0);
        acc01 = __builtin_amdgcn_mfma_f32_16x16x32_bf16(Ah0, Bl1, acc01, 0, 0, 0);
        acc10 = __builtin_amdgcn_mfma_f32_16x16x32_bf16(Ah1, Bl0, acc10, 0, 0, 0);
        acc11 = __builtin_amdgcn_mfma_f32_16x16x32_bf16(Ah1, Bl1, acc11, 0, 0, 0);
        acc00 = __builtin_amdgcn_mfma_f32_16x16x32_bf16(Al0, Bh0, acc00, 0, 0, 0);
        acc01 = __builtin_amdgcn_mfma_f32_16x16x32_bf16(Al0, Bh1, acc01, 0, 0, 0);
        acc10 = __builtin_amdgcn_mfma_f32_16x16x32_bf16(Al1, Bh0, acc10, 0, 0, 0);
        acc11 = __builtin_amdgcn_mfma_f32_16x16x32_bf16(Al1, Bh1, acc11, 0, 0, 0);
        if (more) stageV(bo ^ 16384);
        __syncthreads();
        bo ^= 16384;
    }

    const int rb = wr * 32 + (lane >> 4) * 4;
    const int cb = wc * 32 + fr;
    #pragma unroll
    for (int j = 0; j < 4; ++j) O[(long)(rb + j +  0) * 768 + cb +  0] = acc00[j];
    #pragma unroll
    for (int j = 0; j < 4; ++j) O[(long)(rb + j +  0) * 768 + cb + 16] = acc01[j];
    #pragma unroll
    for (int j = 0; j < 4; ++j) O[(long)(rb + j + 16) * 768 + cb +  0] = acc10[j];
    #pragma unroll
    for (int j = 0; j < 4; ++j) O[(long)(rb + j + 16) * 768 + cb + 16] = acc11[j];
}

extern "C" void kernel_launch(void* const* d_in, const int* in_sizes, int n_in,
                              void* d_out, int out_size, void* d_ws, size_t ws_size,
                              hipStream_t stream)
{
    (void)in_sizes; (void)n_in; (void)out_size; (void)ws_size;
    const float* x      = (const float*)d_in[0];
    const float* Wqkv   = (const float*)d_in[1];
    const float* bqkv   = (const float*)d_in[2];
    const float* Wproj  = (const float*)d_in[3];
    const float* bproj  = (const float*)d_in[4];
    const float* mean   = (const float*)d_in[5];
    const float* logvar = (const float*)d_in[6];
    const float* mixc   = (const float*)d_in[7];
    float* out = (float*)d_out;
    float* ws = (float*)d_ws;
    float* qc     = ws + QC_OFF;
    float* keysT  = ws + KT_OFF;
    float* vc     = ws + VC_OFF;
    float* kmT    = ws + KM_OFF;
    float* energy = ws + EN_OFF;
    float* oat    = ws + OA_OFF;

    // 1) qkv = x @ Wqkv + bqkv, scatter epilogue -> q / keysT / v
    mfma_gemm<1><<<dim3(8,36,1),256,0,stream>>>(
        x,768,0,0, Wqkv,2304,0,0, nullptr,0,0,0, bqkv, 768, 1,
        qc, keysT, vc);
    // 2) key_mix (transposed output kmT[i][row])
    k_mixture<<<768,512,0,stream>>>(mean, logvar, mixc, keysT, kmT);
    // 3) energy[b,h,q,k] = sum_d q[.,d] * kmT[d][k]
    mfma_gemm<0><<<dim3(4,4,24),256,0,stream>>>(
        qc,768,196608,64, kmT,512,256,32768, energy,256,786432,65536,
        nullptr, 64, 12, nullptr,nullptr,nullptr);
    // 4+5) fused: att = softmax(energy)/sqrt(768); out_attn = att @ v
    k_smpv<<<dim3(4,24,1),256,0,stream>>>(energy, vc, oat);
    // 6) out = out_attn @ Wproj + bproj
    mfma_gemm<0><<<dim3(8,12,1),256,0,stream>>>(
        oat,768,0,0, Wproj,768,0,0, out,768,0,0, bproj, 768, 1,
        nullptr,nullptr,nullptr);
}

// Round 14
// 102.092 us; speedup vs baseline: 1.3894x; 1.1120x over previous
//
#include <hip/hip_runtime.h>

#define LOG2E 1.4426950408889634f
#define LN2 0.6931471805599453f

typedef __attribute__((ext_vector_type(8))) short bf16x8;
typedef __attribute__((ext_vector_type(4))) float f32x4;
typedef __attribute__((ext_vector_type(2))) float f32x2;

constexpr int Ee = 768;
constexpr int BN = 512;
// ws layout (floats):
constexpr long QC_OFF = 0;              // q       [512][768]
constexpr long KT_OFF = 393216;         // keysT   [768][512]
constexpr long VC_OFF = 786432;         // v       [512][768]
constexpr long KM_OFF = 1179648;        // kmT     [768][512]
constexpr long EN_OFF = 1572864;        // energy  [24][256][256]
constexpr long OA_OFF = 3145728;        // out_attn[512][768]

__device__ __forceinline__ unsigned pk_hi(float x0, float x1) {
    return (__float_as_uint(x0) >> 16) | (__float_as_uint(x1) & 0xFFFF0000u);
}
__device__ __forceinline__ float rhi(float x) {
    return __uint_as_float(__float_as_uint(x) & 0xFFFF0000u);
}
__device__ __forceinline__ f32x2 pk_fma2(f32x2 a, f32x2 b, f32x2 c) {
    f32x2 d;
    asm("v_pk_fma_f32 %0, %1, %2, %3" : "=v"(d) : "v"(a), "v"(b), "v"(c));
    return d;
}
__device__ __forceinline__ f32x2 pk_add2(f32x2 a, f32x2 b) {
    f32x2 d;
    asm("v_pk_add_f32 %0, %1, %2" : "=v"(d) : "v"(a), "v"(b));
    return d;
}

// ------------- bf16 hi/lo split MFMA GEMM, 64x64 tile, BK=32 ---------------
// C = A@B as AhBh + AhBl + AlBh (bf16 MFMA, fp32 accum). 256 thr = 4 waves;
// wave = 32x32 quadrant = 2x2 frags of v_mfma_f32_16x16x32_bf16.
// tid<128 stage B (in-reg 4x4 transpose -> BsT[n][k]), tid>=128 stage A.
// XOR swizzle (row&7)<<4 on 128B rows. Single-buffered (R13 lesson: dbuf
// halves occupancy and regresses at these grid sizes). EPI=1: qkv scatter.
template<int EPI>
__global__ __launch_bounds__(256)
void mfma_gemm(const float* __restrict__ A, int lda, long sAb, long sAh,
               const float* __restrict__ Bm, int ldb, long sBb, long sBh,
               float* __restrict__ C, int ldc, long sCb, long sCh,
               const float* __restrict__ bias, int K, int Hdiv,
               float* __restrict__ eq, float* __restrict__ ek,
               float* __restrict__ ev)
{
    __shared__ __align__(16) unsigned short sm[4 * 64 * 64]; // Ahi,Alo,Bhi,Blo
    char* const smb = (char*)sm;
    const int tid = threadIdx.x;
    const int m0 = blockIdx.x * 64, n0 = blockIdx.y * 64;
    const int zb = blockIdx.z / Hdiv, zh = blockIdx.z - zb * Hdiv;
    A  += zb * sAb + zh * sAh;
    Bm += zb * sBb + zh * sBh;
    C  += zb * sCb + zh * sCh;

    const int lane = tid & 63, w = tid >> 6;
    const int wr = w >> 1, wc = w & 1;
    const int fr = lane & 15, fko2 = (lane >> 4) * 16;

    const bool isB = tid < 128;
    const int kq = isB ? (tid >> 4) : ((tid - 128) & 7);
    const int nq = tid & 15;
    const int mq = (tid - 128) >> 3;

    auto foff = [](int plane, int row, int cb) {
        return plane * 8192 + row * 128 + (cb ^ ((row & 7) << 4));
    };
    int wo[8];
    if (isB) {
        #pragma unroll
        for (int e = 0; e < 4; ++e) {
            wo[e]     = foff(2, nq * 4 + e, kq * 8);
            wo[e + 4] = foff(3, nq * 4 + e, kq * 8);
        }
    } else {
        #pragma unroll
        for (int r = 0; r < 4; ++r) {
            wo[r]     = foff(0, mq * 4 + r, kq * 8);
            wo[r + 4] = foff(1, mq * 4 + r, kq * 8);
        }
    }
    const int oA0h = foff(0, wr * 32 + fr,      fko2);
    const int oA1h = foff(0, wr * 32 + 16 + fr, fko2);
    const int oA0l = oA0h + 8192, oA1l = oA1h + 8192;
    const int oB0h = foff(2, wc * 32 + fr,      fko2);
    const int oB1h = foff(2, wc * 32 + 16 + fr, fko2);
    const int oB0l = oB0h + 8192, oB1l = oB1h + 8192;

    f32x4 acc00 = {}, acc01 = {}, acc10 = {}, acc11 = {};
    float4 r0, r1, r2, r3;

    auto load_regs = [&](int k0) {
        if (isB) {
            const float* p = &Bm[(long)(k0 + kq * 4) * ldb + n0 + nq * 4];
            r0 = *(const float4*)p; p += ldb;
            r1 = *(const float4*)p; p += ldb;
            r2 = *(const float4*)p; p += ldb;
            r3 = *(const float4*)p;
        } else {
            const float* p = &A[(long)(m0 + mq * 4) * lda + k0 + kq * 4];
            r0 = *(const float4*)p; p += lda;
            r1 = *(const float4*)p; p += lda;
            r2 = *(const float4*)p; p += lda;
            r3 = *(const float4*)p;
        }
    };

    auto cvt_store = [&](const float4& v, int o_hi, int o_lo) {
        uint2 hi; hi.x = pk_hi(v.x, v.y); hi.y = pk_hi(v.z, v.w);
        const float l0 = v.x - rhi(v.x), l1 = v.y - rhi(v.y);
        const float l2 = v.z - rhi(v.z), l3 = v.w - rhi(v.w);
        uint2 lo; lo.x = pk_hi(l0, l1); lo.y = pk_hi(l2, l3);
        *(uint2*)(smb + o_hi) = hi;
        *(uint2*)(smb + o_lo) = lo;
    };

    auto stage = [&]() {
        if (isB) {
            #pragma unroll
            for (int e = 0; e < 4; ++e) {
                float4 col;
                col.x = (&r0.x)[e]; col.y = (&r1.x)[e];
                col.z = (&r2.x)[e]; col.w = (&r3.x)[e];
                cvt_store(col, wo[e], wo[e + 4]);
            }
        } else {
            cvt_store(r0, wo[0], wo[4]);
            cvt_store(r1, wo[1], wo[5]);
            cvt_store(r2, wo[2], wo[6]);
            cvt_store(r3, wo[3], wo[7]);
        }
    };

    load_regs(0);
    for (int k0 = 0; k0 < K; k0 += 32) {
        __syncthreads();
        stage();
        __syncthreads();
        if (k0 + 32 < K) load_regs(k0 + 32);
        const bf16x8 Ah0 = *(const bf16x8*)(smb + oA0h);
        const bf16x8 Ah1 = *(const bf16x8*)(smb + oA1h);
        const bf16x8 Al0 = *(const bf16x8*)(smb + oA0l);
        const bf16x8 Al1 = *(const bf16x8*)(smb + oA1l);
        const bf16x8 Bh0 = *(const bf16x8*)(smb + oB0h);
        const bf16x8 Bh1 = *(const bf16x8*)(smb + oB1h);
        const bf16x8 Bl0 = *(const bf16x8*)(smb + oB0l);
        const bf16x8 Bl1 = *(const bf16x8*)(smb + oB1l);
        acc00 = __builtin_amdgcn_mfma_f32_16x16x32_bf16(Ah0, Bh0, acc00, 0, 0, 0);
        acc01 = __builtin_amdgcn_mfma_f32_16x16x32_bf16(Ah0, Bh1, acc01, 0, 0, 0);
        acc10 = __builtin_amdgcn_mfma_f32_16x16x32_bf16(Ah1, Bh0, acc10, 0, 0, 0);
        acc11 = __builtin_amdgcn_mfma_f32_16x16x32_bf16(Ah1, Bh1, acc11, 0, 0, 0);
        acc00 = __builtin_amdgcn_mfma_f32_16x16x32_bf16(Ah0, Bl0, acc00, 0, 0, 0);
        acc01 = __builtin_amdgcn_mfma_f32_16x16x32_bf16(Ah0, Bl1, acc01, 0, 0, 0);
        acc10 = __builtin_amdgcn_mfma_f32_16x16x32_bf16(Ah1, Bl0, acc10, 0, 0, 0);
        acc11 = __builtin_amdgcn_mfma_f32_16x16x32_bf16(Ah1, Bl1, acc11, 0, 0, 0);
        acc00 = __builtin_amdgcn_mfma_f32_16x16x32_bf16(Al0, Bh0, acc00, 0, 0, 0);
        acc01 = __builtin_amdgcn_mfma_f32_16x16x32_bf16(Al0, Bh1, acc01, 0, 0, 0);
        acc10 = __builtin_amdgcn_mfma_f32_16x16x32_bf16(Al1, Bh0, acc10, 0, 0, 0);
        acc11 = __builtin_amdgcn_mfma_f32_16x16x32_bf16(Al1, Bh1, acc11, 0, 0, 0);
    }

    const int rb = m0 + wr * 32 + (lane >> 4) * 4;
    const int cb = n0 + wc * 32 + fr;
    if (EPI == 1) {
        auto scat = [&](int row, int col, float x) {
            x += bias[col];
            const int i = col / 3, s = col - i * 3;
            if (s == 0)      eq[(long)row * Ee + i] = x;
            else if (s == 1) ek[(long)i * BN + row] = x;
            else             ev[(long)row * Ee + i] = x;
        };
        #pragma unroll
        for (int j = 0; j < 4; ++j) {
            scat(rb + j,      cb,      acc00[j]);
            scat(rb + j,      cb + 16, acc01[j]);
            scat(rb + j + 16, cb,      acc10[j]);
            scat(rb + j + 16, cb + 16, acc11[j]);
        }
    } else {
        const float b0  = bias ? bias[cb]      : 0.f;
        const float b16 = bias ? bias[cb + 16] : 0.f;
        #pragma unroll
        for (int j = 0; j < 4; ++j) C[(long)(rb + j +  0) * ldc + cb +  0] = acc00[j] + b0;
        #pragma unroll
        for (int j = 0; j < 4; ++j) C[(long)(rb + j +  0) * ldc + cb + 16] = acc01[j] + b16;
        #pragma unroll
        for (int j = 0; j < 4; ++j) C[(long)(rb + j + 16) * ldc + cb +  0] = acc10[j] + b0;
        #pragma unroll
        for (int j = 0; j < 4; ++j) C[(long)(rb + j + 16) * ldc + cb + 16] = acc11[j] + b16;
    }
}

// ---------------- Gaussian-mixture logsumexp (R=8, j-split x8, packed) -----
// Issue-floor version (39.5us): packed fp32 quadratic + HW v_exp_f32.
// (R12 lesson: software packed exp2 is 2.2x SLOWER — the trans pipe's
// 16cyc/wave-op beats ~13 VALU issue slots of emulation. Keep HW exp2.)
__global__ __launch_bounds__(512)
void k_mixture(const float* __restrict__ mean, const float* __restrict__ logvar,
               const float* __restrict__ mix, const float* __restrict__ keysT,
               float* __restrict__ kmT)
{
    __shared__ __align__(16) float aS[768], bS[768], cS[768];
    __shared__ float sP[512][9];
    const int i = blockIdx.x;
    const int tid = threadIdx.x;

    for (int j = tid; j < 768; j += 512) {
        const float lv = logvar[i * Ee + j];
        const float mu = mean[i * Ee + j];
        const float istd2 = __builtin_amdgcn_exp2f(-lv * LOG2E);
        aS[j] = -0.5f * LOG2E * istd2;
        bS[j] = LOG2E * mu * istd2;
        cS[j] = fmaf(-0.5f * LOG2E * mu * mu, istd2, LOG2E * (mix[j] - 0.5f * lv));
    }
    __syncthreads();

    const int rg = tid & 63;
    const int jg = tid >> 6;
    f32x2 kvd[8], k2d[8], s2[8];
    #pragma unroll
    for (int q = 0; q < 8; ++q) {
        const float kv = keysT[(long)i * BN + q * 64 + rg];
        const float k2 = kv * kv;
        kvd[q] = (f32x2){kv, kv};
        k2d[q] = (f32x2){k2, k2};
        s2[q] = (f32x2){0.f, 0.f};
    }
    const float4* a4 = (const float4*)(aS + jg * 96);
    const float4* b4 = (const float4*)(bS + jg * 96);
    const float4* c4 = (const float4*)(cS + jg * 96);
    for (int it = 0; it < 24; ++it) {
        const float4 a = a4[it], b = b4[it], c = c4[it];
        const f32x2 a01 = {a.x, a.y}, a23 = {a.z, a.w};
        const f32x2 b01 = {b.x, b.y}, b23 = {b.z, b.w};
        const f32x2 c01 = {c.x, c.y}, c23 = {c.z, c.w};
        #pragma unroll
        for (int q = 0; q < 8; ++q) {
            f32x2 t0 = pk_fma2(a01, k2d[q], pk_fma2(b01, kvd[q], c01));
            f32x2 t1 = pk_fma2(a23, k2d[q], pk_fma2(b23, kvd[q], c23));
            f32x2 e0 = { __builtin_amdgcn_exp2f(t0.x), __builtin_amdgcn_exp2f(t0.y) };
            f32x2 e1 = { __builtin_amdgcn_exp2f(t1.x), __builtin_amdgcn_exp2f(t1.y) };
            s2[q] = pk_add2(s2[q], e0);
            s2[q] = pk_add2(s2[q], e1);
        }
    }
    #pragma unroll
    for (int q = 0; q < 8; ++q)
        sP[q * 64 + rg][jg] = s2[q].x + s2[q].y;
    __syncthreads();

    const float* rp = sP[tid];
    const float t0 = ((rp[0] + rp[1]) + (rp[2] + rp[3]))
                   + ((rp[4] + rp[5]) + (rp[6] + rp[7]));
    kmT[(long)i * BN + tid] = LN2 * __builtin_amdgcn_logf(t0);
}

// ------------- fused softmax + PV: oat tile = softmax(E band) @ v ----------
// Phase 1: softmax of 64x256 energy band -> bf16 hi/lo att in LDS (first V
// tile loads issued BEFORE phase 1 so HBM latency hides under softmax math).
// Phase 2: PV MFMA loop, single-buffered V restaging per K-step.
__global__ __launch_bounds__(256)
void k_smpv(const float* __restrict__ energy, const float* __restrict__ vc,
            float* __restrict__ oat)
{
    __shared__ __align__(16) unsigned short att[32768]; // hi(32KB) + lo(32KB)
    __shared__ __align__(16) unsigned short bv[8192];   // v hi(8KB) + lo(8KB)
    char* const attb = (char*)att;
    char* const bvb  = (char*)bv;
    const int tid = threadIdx.x;
    const int tile = blockIdx.x, bh = blockIdx.y;
    const int b = bh / 12, h = bh - b * 12;
    const float* E = energy + (long)bh * 65536 + (long)tile * 64 * 256;
    const float* V = vc + (long)b * 196608 + h * 64;
    float* O = oat + ((long)b * 256 + tile * 64) * 768 + h * 64;

    const int w = tid >> 6, lane = tid & 63;
    const bool isB = tid < 128;
    const int kq = tid >> 4;
    const int nq = tid & 15;

    float4 r0, r1, r2, r3;
    auto load_regs = [&](int k0) {
        if (isB) {
            const float* p = &V[(long)(k0 + kq * 4) * 768 + nq * 4];
            r0 = *(const float4*)p; p += 768;
            r1 = *(const float4*)p; p += 768;
            r2 = *(const float4*)p; p += 768;
            r3 = *(const float4*)p;
        }
    };
    load_regs(0);   // issue first V tile; latency hides under phase 1

    // ---- phase 1: softmax of 64x256 band into att planes ----
    {
        const int rl = w * 16 + (lane >> 2);   // local row 0..63
        const int mq = (lane & 3) * 64;        // m-quarter base
        float4 ev[16];
        const float* erow = E + (long)rl * 256 + mq;
        #pragma unroll
        for (int t = 0; t < 16; ++t) ev[t] = *(const float4*)(erow + t * 4);
        float mx = -__builtin_inff();
        #pragma unroll
        for (int t = 0; t < 16; ++t)
            mx = fmaxf(mx, fmaxf(fmaxf(ev[t].x, ev[t].y), fmaxf(ev[t].z, ev[t].w)));
        mx = fmaxf(mx, __shfl_xor(mx, 1, 64));
        mx = fmaxf(mx, __shfl_xor(mx, 2, 64));
        float sum = 0.f;
        #pragma unroll
        for (int t = 0; t < 16; ++t) {
            ev[t].x = __builtin_amdgcn_exp2f((ev[t].x - mx) * LOG2E);
            ev[t].y = __builtin_amdgcn_exp2f((ev[t].y - mx) * LOG2E);
            ev[t].z = __builtin_amdgcn_exp2f((ev[t].z - mx) * LOG2E);
            ev[t].w = __builtin_amdgcn_exp2f((ev[t].w - mx) * LOG2E);
            sum += (ev[t].x + ev[t].y) + (ev[t].z + ev[t].w);
        }
        sum += __shfl_xor(sum, 1, 64);
        sum += __shfl_xor(sum, 2, 64);
        const float sc = 1.0f / (sum * 27.712812921102035f);  // * sqrt(768)
        const int rxor = (rl & 7) << 4;
        #pragma unroll
        for (int t = 0; t < 16; ++t) {
            const float x0 = ev[t].x * sc, x1 = ev[t].y * sc;
            const float x2 = ev[t].z * sc, x3 = ev[t].w * sc;
            uint2 hi; hi.x = pk_hi(x0, x1); hi.y = pk_hi(x2, x3);
            const float l0 = x0 - rhi(x0), l1 = x1 - rhi(x1);
            const float l2 = x2 - rhi(x2), l3 = x3 - rhi(x3);
            uint2 lo; lo.x = pk_hi(l0, l1); lo.y = pk_hi(l2, l3);
            const int cb = (mq + t * 4) * 2;
            *(uint2*)(attb + (long)rl * 512 + (cb ^ rxor))         = hi;
            *(uint2*)(attb + 32768 + (long)rl * 512 + (cb ^ rxor)) = lo;
        }
    }

    // ---- phase 2: [64 rows] x [64 d] = att(64x256) @ v(256x64) ----
    const int wr = w >> 1, wc = w & 1;
    const int fr = lane & 15, fko2 = (lane >> 4) * 16;
    const int rA0 = wr * 32 + fr, rA1 = rA0 + 16;
    const int rB0 = wc * 32 + fr, rB1 = rB0 + 16;
    const int xA0 = (rA0 & 7) << 4, xA1 = (rA1 & 7) << 4;
    const int oB0h = rB0 * 128 + (fko2 ^ ((rB0 & 7) << 4));
    const int oB1h = rB1 * 128 + (fko2 ^ ((rB1 & 7) << 4));
    const int oB0l = oB0h + 8192, oB1l = oB1h + 8192;

    int wo[8];
    #pragma unroll
    for (int e = 0; e < 4; ++e) {
        const int row = nq * 4 + e;
        wo[e]     = row * 128 + ((kq * 8) ^ ((row & 7) << 4));
        wo[e + 4] = wo[e] + 8192;
    }

    f32x4 acc00 = {}, acc01 = {}, acc10 = {}, acc11 = {};
    auto cvt_store = [&](const float4& v, int o_hi, int o_lo) {
        uint2 hi; hi.x = pk_hi(v.x, v.y); hi.y = pk_hi(v.z, v.w);
        const float l0 = v.x - rhi(v.x), l1 = v.y - rhi(v.y);
        const float l2 = v.z - rhi(v.z), l3 = v.w - rhi(v.w);
        uint2 lo; lo.x = pk_hi(l0, l1); lo.y = pk_hi(l2, l3);
        *(uint2*)(bvb + o_hi) = hi;
        *(uint2*)(bvb + o_lo) = lo;
    };

    for (int k0 = 0; k0 < 256; k0 += 32) {
        __syncthreads();
        if (isB) {
            #pragma unroll
            for (int e = 0; e < 4; ++e) {
                float4 col;
                col.x = (&r0.x)[e]; col.y = (&r1.x)[e];
                col.z = (&r2.x)[e]; col.w = (&r3.x)[e];
                cvt_store(col, wo[e], wo[e + 4]);
            }
        }
        __syncthreads();
        if (k0 + 32 < 256) load_regs(k0 + 32);
        const int cA = k0 * 2 + fko2;
        const bf16x8 Ah0 = *(const bf16x8*)(attb + (long)rA0 * 512 + (cA ^ xA0));
        const bf16x8 Ah1 = *(const bf16x8*)(attb + (long)rA1 * 512 + (cA ^ xA1));
        const bf16x8 Al0 = *(const bf16x8*)(attb + 32768 + (long)rA0 * 512 + (cA ^ xA0));
        const bf16x8 Al1 = *(const bf16x8*)(attb + 32768 + (long)rA1 * 512 + (cA ^ xA1));
        const bf16x8 Bh0 = *(const bf16x8*)(bvb + oB0h);
        const bf16x8 Bh1 = *(const bf16x8*)(bvb + oB1h);
        const bf16x8 Bl0 = *(const bf16x8*)(bvb + oB0l);
        const bf16x8 Bl1 = *(const bf16x8*)(bvb + oB1l);
        acc00 = __builtin_amdgcn_mfma_f32_16x16x32_bf16(Ah0, Bh0, acc00, 0, 0, 0);
        acc01 = __builtin_amdgcn_mfma_f32_16x16x32_bf16(Ah0, Bh1, acc01, 0, 0, 0);
        acc10 = __builtin_amdgcn_mfma_f32_16x16x32_bf16(Ah1, Bh0, acc10, 0, 0, 0);
        acc11 = __builtin_amdgcn_mfma_f32_16x16x32_bf16(Ah1, Bh1, acc11, 0, 0, 0);
        acc00 = __builtin_amdgcn_mfma_f32_16x16x32_bf16(Ah0, Bl0, acc00, 0, 0, 0);
        acc01 = __builtin_amdgcn_mfma_f32_16x16x32_bf16(Ah0, Bl1, acc01, 0, 0, 0);
        acc10 = __builtin_amdgcn_mfma_f32_16x16x32_bf16(Ah1, Bl0, acc10, 0, 0, 0);
        acc11 = __builtin_amdgcn_mfma_f32_16x16x32_bf16(Ah1, Bl1, acc11, 0, 0, 0);
        acc00 = __builtin_amdgcn_mfma_f32_16x16x32_bf16(Al0, Bh0, acc00, 0, 0, 0);
        acc01 = __builtin_amdgcn_mfma_f32_16x16x32_bf16(Al0, Bh1, acc01, 0, 0, 0);
        acc10 = __builtin_amdgcn_mfma_f32_16x16x32_bf16(Al1, Bh0, acc10, 0, 0, 0);
        acc11 = __builtin_amdgcn_mfma_f32_16x16x32_bf16(Al1, Bh1, acc11, 0, 0, 0);
    }

    const int rb = wr * 32 + (lane >> 4) * 4;
    const int cb = wc * 32 + fr;
    #pragma unroll
    for (int j = 0; j < 4; ++j) O[(long)(rb + j +  0) * 768 + cb +  0] = acc00[j];
    #pragma unroll
    for (int j = 0; j < 4; ++j) O[(long)(rb + j +  0) * 768 + cb + 16] = acc01[j];
    #pragma unroll
    for (int j = 0; j < 4; ++j) O[(long)(rb + j + 16) * 768 + cb +  0] = acc10[j];
    #pragma unroll
    for (int j = 0; j < 4; ++j) O[(long)(rb + j + 16) * 768 + cb + 16] = acc11[j];
}

extern "C" void kernel_launch(void* const* d_in, const int* in_sizes, int n_in,
                              void* d_out, int out_size, void* d_ws, size_t ws_size,
                              hipStream_t stream)
{
    (void)in_sizes; (void)n_in; (void)out_size; (void)ws_size;
    const float* x      = (const float*)d_in[0];
    const float* Wqkv   = (const float*)d_in[1];
    const float* bqkv   = (const float*)d_in[2];
    const float* Wproj  = (const float*)d_in[3];
    const float* bproj  = (const float*)d_in[4];
    const float* mean   = (const float*)d_in[5];
    const float* logvar = (const float*)d_in[6];
    const float* mixc   = (const float*)d_in[7];
    float* out = (float*)d_out;
    float* ws = (float*)d_ws;
    float* qc     = ws + QC_OFF;
    float* keysT  = ws + KT_OFF;
    float* vc     = ws + VC_OFF;
    float* kmT    = ws + KM_OFF;
    float* energy = ws + EN_OFF;
    float* oat    = ws + OA_OFF;

    // 1) qkv = x @ Wqkv + bqkv, scatter epilogue -> q / keysT / v
    mfma_gemm<1><<<dim3(8,36,1),256,0,stream>>>(
        x,768,0,0, Wqkv,2304,0,0, nullptr,0,0,0, bqkv, 768, 1,
        qc, keysT, vc);
    // 2) key_mix (transposed output kmT[i][row])
    k_mixture<<<768,512,0,stream>>>(mean, logvar, mixc, keysT, kmT);
    // 3) energy[b,h,q,k] = sum_d q[.,d] * kmT[d][k]
    mfma_gemm<0><<<dim3(4,4,24),256,0,stream>>>(
        qc,768,196608,64, kmT,512,256,32768, energy,256,786432,65536,
        nullptr, 64, 12, nullptr,nullptr,nullptr);
    // 4+5) fused: att = softmax(energy)/sqrt(768); out_attn = att @ v
    k_smpv<<<dim3(4,24,1),256,0,stream>>>(energy, vc, oat);
    // 6) out = out_attn @ Wproj + bproj
    mfma_gemm<0><<<dim3(8,12,1),256,0,stream>>>(
        oat,768,0,0, Wproj,768,0,0, out,768,0,0, bproj, 768, 1,
        nullptr,nullptr,nullptr);
}

// Round 15
// 100.819 us; speedup vs baseline: 1.4069x; 1.0126x over previous
//
#include <hip/hip_runtime.h>

#define LOG2E 1.4426950408889634f
#define LN2 0.6931471805599453f

typedef __attribute__((ext_vector_type(8))) short bf16x8;
typedef __attribute__((ext_vector_type(4))) float f32x4;
typedef __attribute__((ext_vector_type(2))) float f32x2;

constexpr int Ee = 768;
constexpr int BN = 512;
// ws layout (floats):
constexpr long QC_OFF = 0;              // q       [512][768]
constexpr long KT_OFF = 393216;         // keysT   [768][512]
constexpr long VC_OFF = 786432;         // v       [512][768]
constexpr long KM_OFF = 1179648;        // kmT     [768][512]
constexpr long EN_OFF = 1572864;        // energy  [24][256][256]
constexpr long OA_OFF = 3145728;        // out_attn[512][768]

__device__ __forceinline__ unsigned pk_hi(float x0, float x1) {
    return (__float_as_uint(x0) >> 16) | (__float_as_uint(x1) & 0xFFFF0000u);
}
__device__ __forceinline__ float rhi(float x) {
    return __uint_as_float(__float_as_uint(x) & 0xFFFF0000u);
}
__device__ __forceinline__ f32x2 pk_fma2(f32x2 a, f32x2 b, f32x2 c) {
    f32x2 d;
    asm("v_pk_fma_f32 %0, %1, %2, %3" : "=v"(d) : "v"(a), "v"(b), "v"(c));
    return d;
}
__device__ __forceinline__ f32x2 pk_add2(f32x2 a, f32x2 b) {
    f32x2 d;
    asm("v_pk_add_f32 %0, %1, %2" : "=v"(d) : "v"(a), "v"(b));
    return d;
}

// ------------- bf16 hi/lo split MFMA GEMM, 64x64 tile, BK=32 ---------------
// C = A@B as AhBh + AhBl + AlBh (bf16 MFMA, fp32 accum). 256 thr = 4 waves;
// wave = 32x32 quadrant = 2x2 frags of v_mfma_f32_16x16x32_bf16.
// tid<128 stage B (in-reg 4x4 transpose -> BsT[n][k]), tid>=128 stage A.
// XOR swizzle (row&7)<<4 on 128B rows. Single-buffered LDS (R13: dbuf hurts).
// DEPTH-2 register prefetch (named A/B sets; requires K % 64 == 0).
// swz=1: XCD chunk-swizzle of (bx,by) for L2 panel locality (needs nwg%8==0).
// EPI=1: qkv scatter epilogue.
template<int EPI>
__global__ __launch_bounds__(256)
void mfma_gemm(const float* __restrict__ A, int lda, long sAb, long sAh,
               const float* __restrict__ Bm, int ldb, long sBb, long sBh,
               float* __restrict__ C, int ldc, long sCb, long sCh,
               const float* __restrict__ bias, int K, int Hdiv, int swz,
               float* __restrict__ eq, float* __restrict__ ek,
               float* __restrict__ ev)
{
    __shared__ __align__(16) unsigned short sm[4 * 64 * 64]; // Ahi,Alo,Bhi,Blo
    char* const smb = (char*)sm;
    const int tid = threadIdx.x;
    int bx = blockIdx.x, by = blockIdx.y;
    if (swz) {
        const int nl = gridDim.x * gridDim.y;
        const int lin = blockIdx.x + gridDim.x * blockIdx.y;
        const int lin2 = (lin & 7) * (nl >> 3) + (lin >> 3);
        bx = lin2 % gridDim.x;
        by = lin2 / gridDim.x;
    }
    const int m0 = bx * 64, n0 = by * 64;
    const int zb = blockIdx.z / Hdiv, zh = blockIdx.z - zb * Hdiv;
    A  += zb * sAb + zh * sAh;
    Bm += zb * sBb + zh * sBh;
    C  += zb * sCb + zh * sCh;

    const int lane = tid & 63, w = tid >> 6;
    const int wr = w >> 1, wc = w & 1;
    const int fr = lane & 15, fko2 = (lane >> 4) * 16;

    const bool isB = tid < 128;
    const int kq = isB ? (tid >> 4) : ((tid - 128) & 7);
    const int nq = tid & 15;
    const int mq = (tid - 128) >> 3;

    auto foff = [](int plane, int row, int cb) {
        return plane * 8192 + row * 128 + (cb ^ ((row & 7) << 4));
    };
    int wo[8];
    if (isB) {
        #pragma unroll
        for (int e = 0; e < 4; ++e) {
            wo[e]     = foff(2, nq * 4 + e, kq * 8);
            wo[e + 4] = foff(3, nq * 4 + e, kq * 8);
        }
    } else {
        #pragma unroll
        for (int r = 0; r < 4; ++r) {
            wo[r]     = foff(0, mq * 4 + r, kq * 8);
            wo[r + 4] = foff(1, mq * 4 + r, kq * 8);
        }
    }
    const int oA0h = foff(0, wr * 32 + fr,      fko2);
    const int oA1h = foff(0, wr * 32 + 16 + fr, fko2);
    const int oA0l = oA0h + 8192, oA1l = oA1h + 8192;
    const int oB0h = foff(2, wc * 32 + fr,      fko2);
    const int oB1h = foff(2, wc * 32 + 16 + fr, fko2);
    const int oB0l = oB0h + 8192, oB1l = oB1h + 8192;

    f32x4 acc00 = {}, acc01 = {}, acc10 = {}, acc11 = {};
    float4 pa0, pa1, pa2, pa3;   // prefetch set A
    float4 pb0, pb1, pb2, pb3;   // prefetch set B

    auto load_set = [&](int k0, float4& q0, float4& q1, float4& q2, float4& q3) {
        if (isB) {
            const float* p = &Bm[(long)(k0 + kq * 4) * ldb + n0 + nq * 4];
            q0 = *(const float4*)p; p += ldb;
            q1 = *(const float4*)p; p += ldb;
            q2 = *(const float4*)p; p += ldb;
            q3 = *(const float4*)p;
        } else {
            const float* p = &A[(long)(m0 + mq * 4) * lda + k0 + kq * 4];
            q0 = *(const float4*)p; p += lda;
            q1 = *(const float4*)p; p += lda;
            q2 = *(const float4*)p; p += lda;
            q3 = *(const float4*)p;
        }
    };

    auto cvt_store = [&](const float4& v, int o_hi, int o_lo) {
        uint2 hi; hi.x = pk_hi(v.x, v.y); hi.y = pk_hi(v.z, v.w);
        const float l0 = v.x - rhi(v.x), l1 = v.y - rhi(v.y);
        const float l2 = v.z - rhi(v.z), l3 = v.w - rhi(v.w);
        uint2 lo; lo.x = pk_hi(l0, l1); lo.y = pk_hi(l2, l3);
        *(uint2*)(smb + o_hi) = hi;
        *(uint2*)(smb + o_lo) = lo;
    };

    auto stage_set = [&](const float4& q0, const float4& q1,
                         const float4& q2, const float4& q3) {
        if (isB) {
            #pragma unroll
            for (int e = 0; e < 4; ++e) {
                float4 col;
                col.x = (&q0.x)[e]; col.y = (&q1.x)[e];
                col.z = (&q2.x)[e]; col.w = (&q3.x)[e];
                cvt_store(col, wo[e], wo[e + 4]);
            }
        } else {
            cvt_store(q0, wo[0], wo[4]);
            cvt_store(q1, wo[1], wo[5]);
            cvt_store(q2, wo[2], wo[6]);
            cvt_store(q3, wo[3], wo[7]);
        }
    };

    auto mma = [&]() {
        const bf16x8 Ah0 = *(const bf16x8*)(smb + oA0h);
        const bf16x8 Ah1 = *(const bf16x8*)(smb + oA1h);
        const bf16x8 Al0 = *(const bf16x8*)(smb + oA0l);
        const bf16x8 Al1 = *(const bf16x8*)(smb + oA1l);
        const bf16x8 Bh0 = *(const bf16x8*)(smb + oB0h);
        const bf16x8 Bh1 = *(const bf16x8*)(smb + oB1h);
        const bf16x8 Bl0 = *(const bf16x8*)(smb + oB0l);
        const bf16x8 Bl1 = *(const bf16x8*)(smb + oB1l);
        acc00 = __builtin_amdgcn_mfma_f32_16x16x32_bf16(Ah0, Bh0, acc00, 0, 0, 0);
        acc01 = __builtin_amdgcn_mfma_f32_16x16x32_bf16(Ah0, Bh1, acc01, 0, 0, 0);
        acc10 = __builtin_amdgcn_mfma_f32_16x16x32_bf16(Ah1, Bh0, acc10, 0, 0, 0);
        acc11 = __builtin_amdgcn_mfma_f32_16x16x32_bf16(Ah1, Bh1, acc11, 0, 0, 0);
        acc00 = __builtin_amdgcn_mfma_f32_16x16x32_bf16(Ah0, Bl0, acc00, 0, 0, 0);
        acc01 = __builtin_amdgcn_mfma_f32_16x16x32_bf16(Ah0, Bl1, acc01, 0, 0, 0);
        acc10 = __builtin_amdgcn_mfma_f32_16x16x32_bf16(Ah1, Bl0, acc10, 0, 0, 0);
        acc11 = __builtin_amdgcn_mfma_f32_16x16x32_bf16(Ah1, Bl1, acc11, 0, 0, 0);
        acc00 = __builtin_amdgcn_mfma_f32_16x16x32_bf16(Al0, Bh0, acc00, 0, 0, 0);
        acc01 = __builtin_amdgcn_mfma_f32_16x16x32_bf16(Al0, Bh1, acc01, 0, 0, 0);
        acc10 = __builtin_amdgcn_mfma_f32_16x16x32_bf16(Al1, Bh0, acc10, 0, 0, 0);
        acc11 = __builtin_amdgcn_mfma_f32_16x16x32_bf16(Al1, Bh1, acc11, 0, 0, 0);
    };

    load_set(0, pa0, pa1, pa2, pa3);
    if (32 < K) load_set(32, pb0, pb1, pb2, pb3);
    for (int k0 = 0; k0 < K; k0 += 64) {
        __syncthreads();
        stage_set(pa0, pa1, pa2, pa3);
        __syncthreads();
        if (k0 + 64 < K) load_set(k0 + 64, pa0, pa1, pa2, pa3);
        mma();
        __syncthreads();
        stage_set(pb0, pb1, pb2, pb3);
        __syncthreads();
        if (k0 + 96 < K) load_set(k0 + 96, pb0, pb1, pb2, pb3);
        mma();
    }

    const int rb = m0 + wr * 32 + (lane >> 4) * 4;
    const int cb = n0 + wc * 32 + fr;
    if (EPI == 1) {
        auto scat = [&](int row, int col, float x) {
            x += bias[col];
            const int i = col / 3, s = col - i * 3;
            if (s == 0)      eq[(long)row * Ee + i] = x;
            else if (s == 1) ek[(long)i * BN + row] = x;
            else             ev[(long)row * Ee + i] = x;
        };
        #pragma unroll
        for (int j = 0; j < 4; ++j) {
            scat(rb + j,      cb,      acc00[j]);
            scat(rb + j,      cb + 16, acc01[j]);
            scat(rb + j + 16, cb,      acc10[j]);
            scat(rb + j + 16, cb + 16, acc11[j]);
        }
    } else {
        const float b0  = bias ? bias[cb]      : 0.f;
        const float b16 = bias ? bias[cb + 16] : 0.f;
        #pragma unroll
        for (int j = 0; j < 4; ++j) C[(long)(rb + j +  0) * ldc + cb +  0] = acc00[j] + b0;
        #pragma unroll
        for (int j = 0; j < 4; ++j) C[(long)(rb + j +  0) * ldc + cb + 16] = acc01[j] + b16;
        #pragma unroll
        for (int j = 0; j < 4; ++j) C[(long)(rb + j + 16) * ldc + cb +  0] = acc10[j] + b0;
        #pragma unroll
        for (int j = 0; j < 4; ++j) C[(long)(rb + j + 16) * ldc + cb + 16] = acc11[j] + b16;
    }
}

// ---------------- Gaussian-mixture logsumexp (R=8, j-split x8, packed) -----
// Issue-floor version (38.8us): packed fp32 quadratic + HW v_exp_f32.
// (R12 lesson: software packed exp2 is 2.2x SLOWER — keep HW exp2.)
__global__ __launch_bounds__(512)
void k_mixture(const float* __restrict__ mean, const float* __restrict__ logvar,
               const float* __restrict__ mix, const float* __restrict__ keysT,
               float* __restrict__ kmT)
{
    __shared__ __align__(16) float aS[768], bS[768], cS[768];
    __shared__ float sP[512][9];
    const int i = blockIdx.x;
    const int tid = threadIdx.x;

    for (int j = tid; j < 768; j += 512) {
        const float lv = logvar[i * Ee + j];
        const float mu = mean[i * Ee + j];
        const float istd2 = __builtin_amdgcn_exp2f(-lv * LOG2E);
        aS[j] = -0.5f * LOG2E * istd2;
        bS[j] = LOG2E * mu * istd2;
        cS[j] = fmaf(-0.5f * LOG2E * mu * mu, istd2, LOG2E * (mix[j] - 0.5f * lv));
    }
    __syncthreads();

    const int rg = tid & 63;
    const int jg = tid >> 6;
    f32x2 kvd[8], k2d[8], s2[8];
    #pragma unroll
    for (int q = 0; q < 8; ++q) {
        const float kv = keysT[(long)i * BN + q * 64 + rg];
        const float k2 = kv * kv;
        kvd[q] = (f32x2){kv, kv};
        k2d[q] = (f32x2){k2, k2};
        s2[q] = (f32x2){0.f, 0.f};
    }
    const float4* a4 = (const float4*)(aS + jg * 96);
    const float4* b4 = (const float4*)(bS + jg * 96);
    const float4* c4 = (const float4*)(cS + jg * 96);
    for (int it = 0; it < 24; ++it) {
        const float4 a = a4[it], b = b4[it], c = c4[it];
        const f32x2 a01 = {a.x, a.y}, a23 = {a.z, a.w};
        const f32x2 b01 = {b.x, b.y}, b23 = {b.z, b.w};
        const f32x2 c01 = {c.x, c.y}, c23 = {c.z, c.w};
        #pragma unroll
        for (int q = 0; q < 8; ++q) {
            f32x2 t0 = pk_fma2(a01, k2d[q], pk_fma2(b01, kvd[q], c01));
            f32x2 t1 = pk_fma2(a23, k2d[q], pk_fma2(b23, kvd[q], c23));
            f32x2 e0 = { __builtin_amdgcn_exp2f(t0.x), __builtin_amdgcn_exp2f(t0.y) };
            f32x2 e1 = { __builtin_amdgcn_exp2f(t1.x), __builtin_amdgcn_exp2f(t1.y) };
            s2[q] = pk_add2(s2[q], e0);
            s2[q] = pk_add2(s2[q], e1);
        }
    }
    #pragma unroll
    for (int q = 0; q < 8; ++q)
        sP[q * 64 + rg][jg] = s2[q].x + s2[q].y;
    __syncthreads();

    const float* rp = sP[tid];
    const float t0 = ((rp[0] + rp[1]) + (rp[2] + rp[3]))
                   + ((rp[4] + rp[5]) + (rp[6] + rp[7]));
    kmT[(long)i * BN + tid] = LN2 * __builtin_amdgcn_logf(t0);
}

// ------------- fused softmax + PV: oat tile = softmax(E band) @ v ----------
// Phase 1: softmax of 64x256 energy band -> bf16 hi/lo att in LDS. BOTH
// first V prefetch sets issue before phase 1 (HBM latency hides in softmax).
// Phase 2: PV MFMA loop, depth-2 register prefetch, single-buffered staging.
__global__ __launch_bounds__(256)
void k_smpv(const float* __restrict__ energy, const float* __restrict__ vc,
            float* __restrict__ oat)
{
    __shared__ __align__(16) unsigned short att[32768]; // hi(32KB) + lo(32KB)
    __shared__ __align__(16) unsigned short bv[8192];   // v hi(8KB) + lo(8KB)
    char* const attb = (char*)att;
    char* const bvb  = (char*)bv;
    const int tid = threadIdx.x;
    const int tile = blockIdx.x, bh = blockIdx.y;
    const int b = bh / 12, h = bh - b * 12;
    const float* E = energy + (long)bh * 65536 + (long)tile * 64 * 256;
    const float* V = vc + (long)b * 196608 + h * 64;
    float* O = oat + ((long)b * 256 + tile * 64) * 768 + h * 64;

    const int w = tid >> 6, lane = tid & 63;
    const bool isB = tid < 128;
    const int kq = tid >> 4;
    const int nq = tid & 15;

    float4 pa0, pa1, pa2, pa3, pb0, pb1, pb2, pb3;
    auto load_set = [&](int k0, float4& q0, float4& q1, float4& q2, float4& q3) {
        if (isB) {
            const float* p = &V[(long)(k0 + kq * 4) * 768 + nq * 4];
            q0 = *(const float4*)p; p += 768;
            q1 = *(const float4*)p; p += 768;
            q2 = *(const float4*)p; p += 768;
            q3 = *(const float4*)p;
        }
    };
    load_set(0,  pa0, pa1, pa2, pa3);   // both first V tiles issue here;
    load_set(32, pb0, pb1, pb2, pb3);   // latency hides under phase 1

    // ---- phase 1: softmax of 64x256 band into att planes ----
    {
        const int rl = w * 16 + (lane >> 2);   // local row 0..63
        const int mq = (lane & 3) * 64;        // m-quarter base
        float4 ev[16];
        const float* erow = E + (long)rl * 256 + mq;
        #pragma unroll
        for (int t = 0; t < 16; ++t) ev[t] = *(const float4*)(erow + t * 4);
        float mx = -__builtin_inff();
        #pragma unroll
        for (int t = 0; t < 16; ++t)
            mx = fmaxf(mx, fmaxf(fmaxf(ev[t].x, ev[t].y), fmaxf(ev[t].z, ev[t].w)));
        mx = fmaxf(mx, __shfl_xor(mx, 1, 64));
        mx = fmaxf(mx, __shfl_xor(mx, 2, 64));
        float sum = 0.f;
        #pragma unroll
        for (int t = 0; t < 16; ++t) {
            ev[t].x = __builtin_amdgcn_exp2f((ev[t].x - mx) * LOG2E);
            ev[t].y = __builtin_amdgcn_exp2f((ev[t].y - mx) * LOG2E);
            ev[t].z = __builtin_amdgcn_exp2f((ev[t].z - mx) * LOG2E);
            ev[t].w = __builtin_amdgcn_exp2f((ev[t].w - mx) * LOG2E);
            sum += (ev[t].x + ev[t].y) + (ev[t].z + ev[t].w);
        }
        sum += __shfl_xor(sum, 1, 64);
        sum += __shfl_xor(sum, 2, 64);
        const float sc = 1.0f / (sum * 27.712812921102035f);  // * sqrt(768)
        const int rxor = (rl & 7) << 4;
        #pragma unroll
        for (int t = 0; t < 16; ++t) {
            const float x0 = ev[t].x * sc, x1 = ev[t].y * sc;
            const float x2 = ev[t].z * sc, x3 = ev[t].w * sc;
            uint2 hi; hi.x = pk_hi(x0, x1); hi.y = pk_hi(x2, x3);
            const float l0 = x0 - rhi(x0), l1 = x1 - rhi(x1);
            const float l2 = x2 - rhi(x2), l3 = x3 - rhi(x3);
            uint2 lo; lo.x = pk_hi(l0, l1); lo.y = pk_hi(l2, l3);
            const int cb = (mq + t * 4) * 2;
            *(uint2*)(attb + (long)rl * 512 + (cb ^ rxor))         = hi;
            *(uint2*)(attb + 32768 + (long)rl * 512 + (cb ^ rxor)) = lo;
        }
    }

    // ---- phase 2: [64 rows] x [64 d] = att(64x256) @ v(256x64) ----
    const int wr = w >> 1, wc = w & 1;
    const int fr = lane & 15, fko2 = (lane >> 4) * 16;
    const int rA0 = wr * 32 + fr, rA1 = rA0 + 16;
    const int rB0 = wc * 32 + fr, rB1 = rB0 + 16;
    const int xA0 = (rA0 & 7) << 4, xA1 = (rA1 & 7) << 4;
    const int oB0h = rB0 * 128 + (fko2 ^ ((rB0 & 7) << 4));
    const int oB1h = rB1 * 128 + (fko2 ^ ((rB1 & 7) << 4));
    const int oB0l = oB0h + 8192, oB1l = oB1h + 8192;

    int wo[8];
    #pragma unroll
    for (int e = 0; e < 4; ++e) {
        const int row = nq * 4 + e;
        wo[e]     = row * 128 + ((kq * 8) ^ ((row & 7) << 4));
        wo[e + 4] = wo[e] + 8192;
    }

    f32x4 acc00 = {}, acc01 = {}, acc10 = {}, acc11 = {};
    auto cvt_store = [&](const float4& v, int o_hi, int o_lo) {
        uint2 hi; hi.x = pk_hi(v.x, v.y); hi.y = pk_hi(v.z, v.w);
        const float l0 = v.x - rhi(v.x), l1 = v.y - rhi(v.y);
        const float l2 = v.z - rhi(v.z), l3 = v.w - rhi(v.w);
        uint2 lo; lo.x = pk_hi(l0, l1); lo.y = pk_hi(l2, l3);
        *(uint2*)(bvb + o_hi) = hi;
        *(uint2*)(bvb + o_lo) = lo;
    };
    auto stage_set = [&](const float4& q0, const float4& q1,
                         const float4& q2, const float4& q3) {
        if (isB) {
            #pragma unroll
            for (int e = 0; e < 4; ++e) {
                float4 col;
                col.x = (&q0.x)[e]; col.y = (&q1.x)[e];
                col.z = (&q2.x)[e]; col.w = (&q3.x)[e];
                cvt_store(col, wo[e], wo[e + 4]);
            }
        }
    };
    auto mma = [&](int k0) {
        const int cA = k0 * 2 + fko2;
        const bf16x8 Ah0 = *(const bf16x8*)(attb + (long)rA0 * 512 + (cA ^ xA0));
        const bf16x8 Ah1 = *(const bf16x8*)(attb + (long)rA1 * 512 + (cA ^ xA1));
        const bf16x8 Al0 = *(const bf16x8*)(attb + 32768 + (long)rA0 * 512 + (cA ^ xA0));
        const bf16x8 Al1 = *(const bf16x8*)(attb + 32768 + (long)rA1 * 512 + (cA ^ xA1));
        const bf16x8 Bh0 = *(const bf16x8*)(bvb + oB0h);
        const bf16x8 Bh1 = *(const bf16x8*)(bvb + oB1h);
        const bf16x8 Bl0 = *(const bf16x8*)(bvb + oB0l);
        const bf16x8 Bl1 = *(const bf16x8*)(bvb + oB1l);
        acc00 = __builtin_amdgcn_mfma_f32_16x16x32_bf16(Ah0, Bh0, acc00, 0, 0, 0);
        acc01 = __builtin_amdgcn_mfma_f32_16x16x32_bf16(Ah0, Bh1, acc01, 0, 0, 0);
        acc10 = __builtin_amdgcn_mfma_f32_16x16x32_bf16(Ah1, Bh0, acc10, 0, 0, 0);
        acc11 = __builtin_amdgcn_mfma_f32_16x16x32_bf16(Ah1, Bh1, acc11, 0, 0, 0);
        acc00 = __builtin_amdgcn_mfma_f32_16x16x32_bf16(Ah0, Bl0, acc00, 0, 0, 0);
        acc01 = __builtin_amdgcn_mfma_f32_16x16x32_bf16(Ah0, Bl1, acc01, 0, 0, 0);
        acc10 = __builtin_amdgcn_mfma_f32_16x16x32_bf16(Ah1, Bl0, acc10, 0, 0, 0);
        acc11 = __builtin_amdgcn_mfma_f32_16x16x32_bf16(Ah1, Bl1, acc11, 0, 0, 0);
        acc00 = __builtin_amdgcn_mfma_f32_16x16x32_bf16(Al0, Bh0, acc00, 0, 0, 0);
        acc01 = __builtin_amdgcn_mfma_f32_16x16x32_bf16(Al0, Bh1, acc01, 0, 0, 0);
        acc10 = __builtin_amdgcn_mfma_f32_16x16x32_bf16(Al1, Bh0, acc10, 0, 0, 0);
        acc11 = __builtin_amdgcn_mfma_f32_16x16x32_bf16(Al1, Bh1, acc11, 0, 0, 0);
    };

    for (int k0 = 0; k0 < 256; k0 += 64) {
        __syncthreads();
        stage_set(pa0, pa1, pa2, pa3);
        __syncthreads();
        if (k0 + 64 < 256) load_set(k0 + 64, pa0, pa1, pa2, pa3);
        mma(k0);
        __syncthreads();
        stage_set(pb0, pb1, pb2, pb3);
        __syncthreads();
        if (k0 + 96 < 256) load_set(k0 + 96, pb0, pb1, pb2, pb3);
        mma(k0 + 32);
    }

    const int rb = wr * 32 + (lane >> 4) * 4;
    const int cb = wc * 32 + fr;
    #pragma unroll
    for (int j = 0; j < 4; ++j) O[(long)(rb + j +  0) * 768 + cb +  0] = acc00[j];
    #pragma unroll
    for (int j = 0; j < 4; ++j) O[(long)(rb + j +  0) * 768 + cb + 16] = acc01[j];
    #pragma unroll
    for (int j = 0; j < 4; ++j) O[(long)(rb + j + 16) * 768 + cb +  0] = acc10[j];
    #pragma unroll
    for (int j = 0; j < 4; ++j) O[(long)(rb + j + 16) * 768 + cb + 16] = acc11[j];
}

extern "C" void kernel_launch(void* const* d_in, const int* in_sizes, int n_in,
                              void* d_out, int out_size, void* d_ws, size_t ws_size,
                              hipStream_t stream)
{
    (void)in_sizes; (void)n_in; (void)out_size; (void)ws_size;
    const float* x      = (const float*)d_in[0];
    const float* Wqkv   = (const float*)d_in[1];
    const float* bqkv   = (const float*)d_in[2];
    const float* Wproj  = (const float*)d_in[3];
    const float* bproj  = (const float*)d_in[4];
    const float* mean   = (const float*)d_in[5];
    const float* logvar = (const float*)d_in[6];
    const float* mixc   = (const float*)d_in[7];
    float* out = (float*)d_out;
    float* ws = (float*)d_ws;
    float* qc     = ws + QC_OFF;
    float* keysT  = ws + KT_OFF;
    float* vc     = ws + VC_OFF;
    float* kmT    = ws + KM_OFF;
    float* energy = ws + EN_OFF;
    float* oat    = ws + OA_OFF;

    // 1) qkv = x @ Wqkv + bqkv, scatter epilogue -> q / keysT / v (XCD swz)
    mfma_gemm<1><<<dim3(8,36,1),256,0,stream>>>(
        x,768,0,0, Wqkv,2304,0,0, nullptr,0,0,0, bqkv, 768, 1, 1,
        qc, keysT, vc);
    // 2) key_mix (transposed output kmT[i][row])
    k_mixture<<<768,512,0,stream>>>(mean, logvar, mixc, keysT, kmT);
    // 3) energy[b,h,q,k] = sum_d q[.,d] * kmT[d][k]
    mfma_gemm<0><<<dim3(4,4,24),256,0,stream>>>(
        qc,768,196608,64, kmT,512,256,32768, energy,256,786432,65536,
        nullptr, 64, 12, 0, nullptr,nullptr,nullptr);
    // 4+5) fused: att = softmax(energy)/sqrt(768); out_attn = att @ v
    k_smpv<<<dim3(4,24,1),256,0,stream>>>(energy, vc, oat);
    // 6) out = out_attn @ Wproj + bproj (XCD swz)
    mfma_gemm<0><<<dim3(8,12,1),256,0,stream>>>(
        oat,768,0,0, Wproj,768,0,0, out,768,0,0, bproj, 768, 1, 1,
        nullptr,nullptr,nullptr);
}